// Round 5
// baseline (586.965 us; speedup 1.0000x reference)
//
#include <hip/hip_runtime.h>
#include <math.h>

#define NEG 0.2f

typedef __bf16 bf16x8 __attribute__((ext_vector_type(8)));
typedef float  f32x4  __attribute__((ext_vector_type(4)));

// ---------------------------------------------------------------------------
// Fused: W1 pre-swizzle (blocks 0..15) + histogram+rank (remaining blocks).
// W1b slot i = (ch*4+lk)*64 + n holds 8 bf16: W1[ch*32+lk*8+j][n], j=0..7.
// ---------------------------------------------------------------------------
__global__ void histw1_k(const int* __restrict__ ei, int E, int Nn,
                         int* __restrict__ deg, int* __restrict__ rank,
                         const float* __restrict__ W1, __bf16* __restrict__ W1b)
{
    if (blockIdx.x < 16) {
        int i = blockIdx.x * 256 + threadIdx.x;   // 0..4095
        int n = i & 63;
        int k0 = (i >> 6) * 8;                    // (ch*4+lk)*8 == ch*32+lk*8
#pragma unroll
        for (int j = 0; j < 8; ++j)
            W1b[(size_t)i * 8 + j] = (__bf16)W1[(size_t)(k0 + j) * 64 + n];
        return;
    }
    int e = (blockIdx.x - 16) * 256 + threadIdx.x;
    int Ep = E + Nn;
    if (e >= Ep) return;
    int d = (e < E) ? ei[E + e] : e - E;
    rank[e] = atomicAdd(&deg[d], 1);
}

__global__ void scan_a_k(const int* __restrict__ deg, int Nn, int* __restrict__ bsum)
{
    __shared__ int tmp[256];
    int t = threadIdx.x;
    int base = blockIdx.x * 1024 + t * 4;
    int s = 0;
#pragma unroll
    for (int j = 0; j < 4; ++j) { int i = base + j; if (i < Nn) s += deg[i]; }
    tmp[t] = s;
    __syncthreads();
    for (int off = 1; off < 256; off <<= 1) {
        int a = (t >= off) ? tmp[t - off] : 0;
        __syncthreads();
        tmp[t] += a;
        __syncthreads();
    }
    if (t == 255) bsum[blockIdx.x] = tmp[255];
}

__global__ void scan_b_k(int* __restrict__ bsum, int nb)
{
    __shared__ int tmp[256];
    int t = threadIdx.x;
    int v = (t < nb) ? bsum[t] : 0;
    tmp[t] = v;
    __syncthreads();
    for (int off = 1; off < 256; off <<= 1) {
        int a = (t >= off) ? tmp[t - off] : 0;
        __syncthreads();
        tmp[t] += a;
        __syncthreads();
    }
    if (t < nb) bsum[t] = tmp[t] - v;  // exclusive
}

__global__ void scan_c_k(const int* __restrict__ deg, int Nn, const int* __restrict__ boff,
                         int* __restrict__ rowptr)
{
    __shared__ int tmp[256];
    int t = threadIdx.x;
    int base = blockIdx.x * 1024 + t * 4;
    int v[4];
    int s = 0;
#pragma unroll
    for (int j = 0; j < 4; ++j) {
        int i = base + j;
        v[j] = (i < Nn) ? deg[i] : 0;
        s += v[j];
    }
    tmp[t] = s;
    __syncthreads();
    for (int off = 1; off < 256; off <<= 1) {
        int a = (t >= off) ? tmp[t - off] : 0;
        __syncthreads();
        tmp[t] += a;
        __syncthreads();
    }
    int excl = boff[blockIdx.x] + tmp[t] - s;
#pragma unroll
    for (int j = 0; j < 4; ++j) {
        int i = base + j;
        if (i < Nn) {
            rowptr[i] = excl;
            excl += v[j];
            if (i == Nn - 1) rowptr[Nn] = excl;
        }
    }
}

// ---------------------------------------------------------------------------
// Atomic-free CSR scatter (rank-based, proven fastest variant).
// ---------------------------------------------------------------------------
__global__ void scat2_k(const int* __restrict__ ei, int E, int Nn,
                        const int* __restrict__ rowptr, const int* __restrict__ rank,
                        int* __restrict__ csr)
{
    int e = blockIdx.x * 256 + threadIdx.x;
    int Ep = E + Nn;
    if (e >= Ep) return;
    int s, d;
    if (e < E) { s = ei[e]; d = ei[E + e]; } else { s = d = e - E; }
    csr[rowptr[d] + rank[e]] = s;
}

// ---------------------------------------------------------------------------
// K1: h1b[N,64](bf16) = x[N,512] @ W1[512,64] via bf16 MFMA (16x16x32), plus
// fused per-(node,head) attention dots from the f32 accumulators.
// C/D: col = lane&15, row = (lane>>4)*4 + reg (verified m89).
// ---------------------------------------------------------------------------
__global__ __launch_bounds__(256, 4) void gemm1a_k(const float* __restrict__ x,
                                                   const __bf16* __restrict__ W1b,
                                                   const float* __restrict__ asrc,
                                                   const float* __restrict__ adst,
                                                   __bf16* __restrict__ h1b,
                                                   float* __restrict__ as1,
                                                   float* __restrict__ ad1, int Nn)
{
    int t = threadIdx.x;
    int wave = t >> 6, lane = t & 63;
    int lm = lane & 15, lk = lane >> 4;
    int rowa = blockIdx.x * 64 + wave * 16 + lm;          // A: m = lane&15
    const float* xrow = x + (size_t)(rowa < Nn ? rowa : 0) * 512;
    f32x4 acc[4] = {};
#pragma unroll
    for (int ch = 0; ch < 16; ++ch) {
        float4 a0 = *(const float4*)(xrow + ch * 32 + lk * 8);
        float4 a1 = *(const float4*)(xrow + ch * 32 + lk * 8 + 4);
        bf16x8 af;
        af[0] = (__bf16)a0.x; af[1] = (__bf16)a0.y;
        af[2] = (__bf16)a0.z; af[3] = (__bf16)a0.w;
        af[4] = (__bf16)a1.x; af[5] = (__bf16)a1.y;
        af[6] = (__bf16)a1.z; af[7] = (__bf16)a1.w;
#pragma unroll
        for (int nt = 0; nt < 4; ++nt) {
            bf16x8 bf = *(const bf16x8*)(W1b + ((size_t)((ch * 4 + lk) * 64) + nt * 16 + lm) * 8);
            acc[nt] = __builtin_amdgcn_mfma_f32_16x16x32_bf16(af, bf, acc[nt], 0, 0, 0);
        }
    }
    int rowbase = blockIdx.x * 64 + wave * 16 + lk * 4;
    // h1 store (bf16)
#pragma unroll
    for (int nt = 0; nt < 4; ++nt) {
#pragma unroll
        for (int j = 0; j < 4; ++j) {
            int gr = rowbase + j;
            if (gr < Nn) h1b[(size_t)gr * 64 + nt * 16 + lm] = (__bf16)acc[nt][j];
        }
    }
    // fused attention dots (f32 path)
#pragma unroll
    for (int nt = 0; nt < 4; ++nt) {
        float ws = asrc[nt * 16 + lm];
        float wd = adst[nt * 16 + lm];
#pragma unroll
        for (int j = 0; j < 4; ++j) {
            float sv = acc[nt][j] * ws;
            float dv = acc[nt][j] * wd;
            sv += __shfl_xor(sv, 1); dv += __shfl_xor(dv, 1);
            sv += __shfl_xor(sv, 2); dv += __shfl_xor(dv, 2);
            sv += __shfl_xor(sv, 4); dv += __shfl_xor(dv, 4);
            int gr = rowbase + j;
            if ((lm & 7) == 0 && gr < Nn) {
                int hh = nt * 2 + (lm >> 3);
                as1[(size_t)gr * 8 + hh] = sv;
                ad1[(size_t)gr * 8 + hh] = dv;
            }
        }
    }
}

// ---------------------------------------------------------------------------
// Layer-1 fused softmax+aggregate + node2. One wave per dst node.
// NEW lane map: 8 lanes/edge, each lane owns head c8 = lane&7 and channels
// [c8*8, c8*8+8) via ONE bf16x8 16B load. 8 edge-slots x 4-deep branchless
// unroll = 32 edges in flight, no serial tail (clamped csr idx + e=-1e30 ->
// p=0 masking; clamp re-reads the same cache lines, so zero extra traffic).
// ---------------------------------------------------------------------------
__global__ __launch_bounds__(256, 4) void agg1n_k(const int* __restrict__ csr,
                                                  const int* __restrict__ rowptr,
                                                  const float* __restrict__ as1,
                                                  const float* __restrict__ ad1,
                                                  const __bf16* __restrict__ h1b,
                                                  const float* __restrict__ b1,
                                                  const float* __restrict__ W2,
                                                  const float* __restrict__ as2w,
                                                  const float* __restrict__ ad2w,
                                                  float* __restrict__ h2,
                                                  float* __restrict__ as2,
                                                  float* __restrict__ ad2, int Nn)
{
    __shared__ float W2s[640];
    for (int i = threadIdx.x; i < 640; i += 256) W2s[i] = W2[i];
    __syncthreads();   // before any early exit (divergent-barrier safety)

    int wid = (blockIdx.x * 256 + threadIdx.x) >> 6;
    if (wid >= Nn) return;
    int lane = threadIdx.x & 63;
    int sub = lane >> 3;        // edge slot 0..7
    int c8  = lane & 7;         // head AND channel-group index
    float advh = ad1[(size_t)wid * 8 + c8];
    int start = rowptr[wid];
    int len = rowptr[wid + 1] - start;
    float accp = 0.f;
    float accv[8] = {};
    for (int i = sub; i < len; i += 32) {
        int idx = start + i;
        bool k1 = i + 8 < len, k2 = i + 16 < len, k3 = i + 24 < len;
        int s0 = csr[idx];
        int s1 = csr[idx + (k1 ? 8 : 0)];
        int s2 = csr[idx + (k2 ? 16 : 0)];
        int s3 = csr[idx + (k3 ? 24 : 0)];
        float e0 = as1[(size_t)s0 * 8 + c8] + advh;
        float e1 = as1[(size_t)s1 * 8 + c8] + advh;
        float e2 = as1[(size_t)s2 * 8 + c8] + advh;
        float e3 = as1[(size_t)s3 * 8 + c8] + advh;
        bf16x8 hv0 = *(const bf16x8*)(h1b + (size_t)s0 * 64 + c8 * 8);
        bf16x8 hv1 = *(const bf16x8*)(h1b + (size_t)s1 * 64 + c8 * 8);
        bf16x8 hv2 = *(const bf16x8*)(h1b + (size_t)s2 * 64 + c8 * 8);
        bf16x8 hv3 = *(const bf16x8*)(h1b + (size_t)s3 * 64 + c8 * 8);
        e0 = e0 > 0.f ? e0 : NEG * e0;
        e1 = e1 > 0.f ? e1 : NEG * e1;
        e2 = e2 > 0.f ? e2 : NEG * e2;
        e3 = e3 > 0.f ? e3 : NEG * e3;
        if (!k1) e1 = -1e30f;           // masked slots -> p = 0
        if (!k2) e2 = -1e30f;
        if (!k3) e3 = -1e30f;
        float p0 = __expf(e0), p1 = __expf(e1), p2 = __expf(e2), p3 = __expf(e3);
        accp += (p0 + p1) + (p2 + p3);
#pragma unroll
        for (int c = 0; c < 8; ++c)
            accv[c] += p0 * (float)hv0[c] + p1 * (float)hv1[c]
                     + p2 * (float)hv2[c] + p3 * (float)hv3[c];
    }
    // reduce across the 8 edge-slots (lane bits 3..5)
#pragma unroll
    for (int m = 8; m <= 32; m <<= 1) {
        accp += __shfl_xor(accp, m);
#pragma unroll
        for (int c = 0; c < 8; ++c) accv[c] += __shfl_xor(accv[c], m);
    }

    // ---- fused node2: bias + ELU + 64x10 matvec + layer-2 attn dots ----
    float inv = 1.f / (accp + 1e-16f);
    float4 ba = *(const float4*)(b1 + c8 * 8);
    float4 bb = *(const float4*)(b1 + c8 * 8 + 4);
    float g[8];
    g[0] = accv[0] * inv + ba.x;
    g[1] = accv[1] * inv + ba.y;
    g[2] = accv[2] * inv + ba.z;
    g[3] = accv[3] * inv + ba.w;
    g[4] = accv[4] * inv + bb.x;
    g[5] = accv[5] * inv + bb.y;
    g[6] = accv[6] * inv + bb.z;
    g[7] = accv[7] * inv + bb.w;
#pragma unroll
    for (int c = 0; c < 8; ++c) g[c] = g[c] > 0.f ? g[c] : expm1f(g[c]);
    int k0 = c8 * 8;
    float aj[10];
#pragma unroll
    for (int j = 0; j < 10; ++j) {
        float a = 0.f;
#pragma unroll
        for (int c = 0; c < 8; ++c) a += g[c] * W2s[(k0 + c) * 10 + j];
        aj[j] = a;
    }
#pragma unroll
    for (int m = 1; m <= 4; m <<= 1) {
#pragma unroll
        for (int j = 0; j < 10; ++j) aj[j] += __shfl_xor(aj[j], m);
    }
    if (lane == 0) {
        float s2 = 0.f, d2 = 0.f;
#pragma unroll
        for (int j = 0; j < 10; ++j) { s2 += aj[j] * as2w[j]; d2 += aj[j] * ad2w[j]; }
        *(float4*)(h2 + (size_t)wid * 16 + 0) = make_float4(aj[0], aj[1], aj[2], aj[3]);
        *(float4*)(h2 + (size_t)wid * 16 + 4) = make_float4(aj[4], aj[5], aj[6], aj[7]);
        h2[(size_t)wid * 16 + 8] = aj[8];
        h2[(size_t)wid * 16 + 9] = aj[9];
        as2[wid] = s2;
        ad2[wid] = d2;
    }
}

// ---------------------------------------------------------------------------
// Layer-2 fused softmax+aggregate + bias + log_softmax. One wave per dst.
// NEW lane map: 8 lanes/edge; lane c2=lane&7 owns channels {2c2, 2c2+1}
// (active c2<5, float2 load). 8 slots x 4-deep branchless = 32 edges in
// flight, no serial tail.
// ---------------------------------------------------------------------------
__global__ __launch_bounds__(256, 4) void agg2l_k(const int* __restrict__ csr,
                                                  const int* __restrict__ rowptr,
                                                  const float* __restrict__ as2,
                                                  const float* __restrict__ ad2,
                                                  const float* __restrict__ h2,
                                                  const float* __restrict__ b2,
                                                  float* __restrict__ out, int Nn)
{
    int wid = (blockIdx.x * 256 + threadIdx.x) >> 6;
    if (wid >= Nn) return;
    int lane = threadIdx.x & 63;
    int sub = lane >> 3;
    int c2 = lane & 7;
    bool act = (c2 < 5);
    float adv = ad2[wid];
    int start = rowptr[wid];
    int len = rowptr[wid + 1] - start;
    float accp = 0.f, av0 = 0.f, av1 = 0.f;
    const float2 z2 = make_float2(0.f, 0.f);
    for (int i = sub; i < len; i += 32) {
        int idx = start + i;
        bool k1 = i + 8 < len, k2 = i + 16 < len, k3 = i + 24 < len;
        int s0 = csr[idx];
        int s1 = csr[idx + (k1 ? 8 : 0)];
        int s2 = csr[idx + (k2 ? 16 : 0)];
        int s3 = csr[idx + (k3 ? 24 : 0)];
        float e0 = as2[s0] + adv;
        float e1 = as2[s1] + adv;
        float e2 = as2[s2] + adv;
        float e3 = as2[s3] + adv;
        float2 v0 = act ? *(const float2*)(h2 + (size_t)s0 * 16 + c2 * 2) : z2;
        float2 v1 = act ? *(const float2*)(h2 + (size_t)s1 * 16 + c2 * 2) : z2;
        float2 v2 = act ? *(const float2*)(h2 + (size_t)s2 * 16 + c2 * 2) : z2;
        float2 v3 = act ? *(const float2*)(h2 + (size_t)s3 * 16 + c2 * 2) : z2;
        e0 = e0 > 0.f ? e0 : NEG * e0;
        e1 = e1 > 0.f ? e1 : NEG * e1;
        e2 = e2 > 0.f ? e2 : NEG * e2;
        e3 = e3 > 0.f ? e3 : NEG * e3;
        if (!k1) e1 = -1e30f;
        if (!k2) e2 = -1e30f;
        if (!k3) e3 = -1e30f;
        float p0 = __expf(e0), p1 = __expf(e1), p2 = __expf(e2), p3 = __expf(e3);
        accp += (p0 + p1) + (p2 + p3);
        av0 += p0 * v0.x + p1 * v1.x + p2 * v2.x + p3 * v3.x;
        av1 += p0 * v0.y + p1 * v1.y + p2 * v2.y + p3 * v3.y;
    }
#pragma unroll
    for (int m = 8; m <= 32; m <<= 1) {
        accp += __shfl_xor(accp, m);
        av0  += __shfl_xor(av0, m);
        av1  += __shfl_xor(av1, m);
    }

    // ---- fused bias + log_softmax over the 10 classes (5 active lanes) ----
    float inv = 1.f / (accp + 1e-16f);
    float z0 = act ? av0 * inv + b2[c2 * 2]     : -1e30f;
    float z1 = act ? av1 * inv + b2[c2 * 2 + 1] : -1e30f;
    float m = fmaxf(z0, z1);
    m = fmaxf(m, __shfl_xor(m, 1));
    m = fmaxf(m, __shfl_xor(m, 2));
    m = fmaxf(m, __shfl_xor(m, 4));
    float ps = act ? expf(z0 - m) + expf(z1 - m) : 0.f;
    ps += __shfl_xor(ps, 1);
    ps += __shfl_xor(ps, 2);
    ps += __shfl_xor(ps, 4);
    float lse = m + logf(ps);
    if (sub == 0 && act)
        *(float2*)(out + (size_t)wid * 10 + c2 * 2) = make_float2(z0 - lse, z1 - lse);
}

// ---------------------------------------------------------------------------
extern "C" void kernel_launch(void* const* d_in, const int* in_sizes, int n_in,
                              void* d_out, int out_size, void* d_ws, size_t ws_size,
                              hipStream_t stream)
{
    const float* x     = (const float*)d_in[0];
    const float* W1    = (const float*)d_in[1];
    const float* asrc1 = (const float*)d_in[2];
    const float* adst1 = (const float*)d_in[3];
    const float* b1    = (const float*)d_in[4];
    const float* W2    = (const float*)d_in[5];
    const float* asrc2 = (const float*)d_in[6];
    const float* adst2 = (const float*)d_in[7];
    const float* b2    = (const float*)d_in[8];
    const int*   ei    = (const int*)d_in[9];
    float* out = (float*)d_out;

    int F  = in_sizes[1] / 64;       // 512
    int Nn = in_sizes[0] / F;        // 100000
    int E  = in_sizes[9] / 2;        // 1600000
    int Ep = E + Nn;
    int nb = (Nn + 1023) / 1024;

    float* f = (float*)d_ws;
    __bf16* w1b = (__bf16*)f;  f += 512 * 64 / 2;      // 64KB, 16B-aligned
    __bf16* h1b = (__bf16*)f;  f += (size_t)Nn * 32;   // Nn*64 bf16
    float* as1  = f;  f += (size_t)Nn * 8;
    float* ad1  = f;  f += (size_t)Nn * 8;
    float* h2   = f;  f += (size_t)Nn * 16;
    float* as2  = f;  f += Nn;
    float* ad2  = f;  f += Nn;
    int* ip = (int*)f;
    int* deg    = ip;  ip += Nn;
    int* rowptr = ip;  ip += Nn + 1;
    int* bsum   = ip;  ip += 256;
    int* rank   = ip;  ip += Ep;
    int* csr    = ip;  ip += Ep;

    int nbS = (Ep + 255) / 256;

    // CSR histogram + W1 swizzle (fused, independent)
    hipMemsetAsync(deg, 0, (size_t)Nn * sizeof(int), stream);
    histw1_k<<<16 + nbS, 256, 0, stream>>>(ei, E, Nn, deg, rank, W1, w1b);

    // rowptr scan
    scan_a_k<<<nb, 256, 0, stream>>>(deg, Nn, bsum);
    scan_b_k<<<1, 256, 0, stream>>>(bsum, nb);
    scan_c_k<<<nb, 256, 0, stream>>>(deg, Nn, bsum, rowptr);

    // CSR scatter (atomic-free)
    scat2_k<<<nbS, 256, 0, stream>>>(ei, E, Nn, rowptr, rank, csr);

    // Layer-1 GEMM (+attn dots, bf16 h1 store)
    gemm1a_k<<<(Nn + 63) / 64, 256, 0, stream>>>(x, w1b, asrc1, adst1, h1b, as1, ad1, Nn);

    // Layer-1 aggregate + fused node2 (bias/ELU/GEMM2/attn2 dots)
    agg1n_k<<<(Nn + 3) / 4, 256, 0, stream>>>(csr, rowptr, as1, ad1, h1b,
                                              b1, W2, asrc2, adst2, h2, as2, ad2, Nn);

    // Layer-2 aggregate + fused bias + log_softmax
    agg2l_k<<<(Nn + 3) / 4, 256, 0, stream>>>(csr, rowptr, as2, ad2, h2, b2, out, Nn);
}

// Round 6
// 566.018 us; speedup vs baseline: 1.0370x; 1.0370x over previous
//
#include <hip/hip_runtime.h>
#include <math.h>

#define NEG 0.2f

typedef __bf16 bf16x8 __attribute__((ext_vector_type(8)));
typedef __bf16 bf16x4 __attribute__((ext_vector_type(4)));
typedef float  f32x4  __attribute__((ext_vector_type(4)));

// ---------------------------------------------------------------------------
// Fused: W1 pre-swizzle (blocks 0..15) + histogram+rank (remaining blocks).
// W1b slot i = (ch*4+lk)*64 + n holds 8 bf16: W1[ch*32+lk*8+j][n], j=0..7.
// ---------------------------------------------------------------------------
__global__ void histw1_k(const int* __restrict__ ei, int E, int Nn,
                         int* __restrict__ deg, int* __restrict__ rank,
                         const float* __restrict__ W1, __bf16* __restrict__ W1b)
{
    if (blockIdx.x < 16) {
        int i = blockIdx.x * 256 + threadIdx.x;   // 0..4095
        int n = i & 63;
        int k0 = (i >> 6) * 8;                    // (ch*4+lk)*8 == ch*32+lk*8
#pragma unroll
        for (int j = 0; j < 8; ++j)
            W1b[(size_t)i * 8 + j] = (__bf16)W1[(size_t)(k0 + j) * 64 + n];
        return;
    }
    int e = (blockIdx.x - 16) * 256 + threadIdx.x;
    int Ep = E + Nn;
    if (e >= Ep) return;
    int d = (e < E) ? ei[E + e] : e - E;
    rank[e] = atomicAdd(&deg[d], 1);
}

__global__ void scan_a_k(const int* __restrict__ deg, int Nn, int* __restrict__ bsum)
{
    __shared__ int tmp[256];
    int t = threadIdx.x;
    int base = blockIdx.x * 1024 + t * 4;
    int s = 0;
#pragma unroll
    for (int j = 0; j < 4; ++j) { int i = base + j; if (i < Nn) s += deg[i]; }
    tmp[t] = s;
    __syncthreads();
    for (int off = 1; off < 256; off <<= 1) {
        int a = (t >= off) ? tmp[t - off] : 0;
        __syncthreads();
        tmp[t] += a;
        __syncthreads();
    }
    if (t == 255) bsum[blockIdx.x] = tmp[255];
}

// ---------------------------------------------------------------------------
// Fused scan_b+scan_c: every block redundantly computes the exclusive prefix
// of the (<=256) block sums in LDS (98 ints - trivial), then scans its own
// 1024 degrees and writes rowptr. Saves one dispatch + its launch gap.
// ---------------------------------------------------------------------------
__global__ void scan_bc_k(const int* __restrict__ deg, int Nn,
                          const int* __restrict__ bsum, int nb,
                          int* __restrict__ rowptr)
{
    __shared__ int btmp[256];
    __shared__ int tmp[256];
    int t = threadIdx.x;
    btmp[t] = (t < nb) ? bsum[t] : 0;
    __syncthreads();
    for (int off = 1; off < 256; off <<= 1) {
        int a = (t >= off) ? btmp[t - off] : 0;
        __syncthreads();
        btmp[t] += a;
        __syncthreads();
    }
    int boff = (blockIdx.x == 0) ? 0 : btmp[blockIdx.x - 1];   // exclusive

    int base = blockIdx.x * 1024 + t * 4;
    int v[4];
    int s = 0;
#pragma unroll
    for (int j = 0; j < 4; ++j) {
        int i = base + j;
        v[j] = (i < Nn) ? deg[i] : 0;
        s += v[j];
    }
    tmp[t] = s;
    __syncthreads();
    for (int off = 1; off < 256; off <<= 1) {
        int a = (t >= off) ? tmp[t - off] : 0;
        __syncthreads();
        tmp[t] += a;
        __syncthreads();
    }
    int excl = boff + tmp[t] - s;
#pragma unroll
    for (int j = 0; j < 4; ++j) {
        int i = base + j;
        if (i < Nn) {
            rowptr[i] = excl;
            excl += v[j];
            if (i == Nn - 1) rowptr[Nn] = excl;
        }
    }
}

// ---------------------------------------------------------------------------
// Fused: gemm1 (+attention dots) on blocks [0,nbG) + atomic-free CSR scatter
// on blocks [nbG,..). (r2->r3 measured -3us for this fusion.)
// GEMM: h1b[N,64](bf16) = x[N,512] @ W1[512,64] via bf16 MFMA (16x16x32),
// attention dots from the f32 accumulators.
// C/D: col = lane&15, row = (lane>>4)*4 + reg (verified m89).
// ---------------------------------------------------------------------------
__global__ __launch_bounds__(256, 4) void scatgemm_k(
    const float* __restrict__ x, const __bf16* __restrict__ W1b,
    const float* __restrict__ asrc, const float* __restrict__ adst,
    __bf16* __restrict__ h1b, float* __restrict__ as1, float* __restrict__ ad1,
    const int* __restrict__ ei, int E,
    const int* __restrict__ rowptr, const int* __restrict__ rank,
    int* __restrict__ csr, int Nn, int nbG)
{
    if ((int)blockIdx.x >= nbG) {
        // ---- scatter path ----
        int e = ((int)blockIdx.x - nbG) * 256 + threadIdx.x;
        int Ep = E + Nn;
        if (e >= Ep) return;
        int s, d;
        if (e < E) { s = ei[e]; d = ei[E + e]; } else { s = d = e - E; }
        csr[rowptr[d] + rank[e]] = s;
        return;
    }
    // ---- gemm path ----
    int t = threadIdx.x;
    int wave = t >> 6, lane = t & 63;
    int lm = lane & 15, lk = lane >> 4;
    int rowa = blockIdx.x * 64 + wave * 16 + lm;          // A: m = lane&15
    const float* xrow = x + (size_t)(rowa < Nn ? rowa : 0) * 512;
    f32x4 acc[4] = {};
#pragma unroll
    for (int ch = 0; ch < 16; ++ch) {
        float4 a0 = *(const float4*)(xrow + ch * 32 + lk * 8);
        float4 a1 = *(const float4*)(xrow + ch * 32 + lk * 8 + 4);
        bf16x8 af;
        af[0] = (__bf16)a0.x; af[1] = (__bf16)a0.y;
        af[2] = (__bf16)a0.z; af[3] = (__bf16)a0.w;
        af[4] = (__bf16)a1.x; af[5] = (__bf16)a1.y;
        af[6] = (__bf16)a1.z; af[7] = (__bf16)a1.w;
#pragma unroll
        for (int nt = 0; nt < 4; ++nt) {
            bf16x8 bf = *(const bf16x8*)(W1b + ((size_t)((ch * 4 + lk) * 64) + nt * 16 + lm) * 8);
            acc[nt] = __builtin_amdgcn_mfma_f32_16x16x32_bf16(af, bf, acc[nt], 0, 0, 0);
        }
    }
    int rowbase = blockIdx.x * 64 + wave * 16 + lk * 4;
    // h1 store (bf16)
#pragma unroll
    for (int nt = 0; nt < 4; ++nt) {
#pragma unroll
        for (int j = 0; j < 4; ++j) {
            int gr = rowbase + j;
            if (gr < Nn) h1b[(size_t)gr * 64 + nt * 16 + lm] = (__bf16)acc[nt][j];
        }
    }
    // fused attention dots (f32 path)
#pragma unroll
    for (int nt = 0; nt < 4; ++nt) {
        float ws = asrc[nt * 16 + lm];
        float wd = adst[nt * 16 + lm];
#pragma unroll
        for (int j = 0; j < 4; ++j) {
            float sv = acc[nt][j] * ws;
            float dv = acc[nt][j] * wd;
            sv += __shfl_xor(sv, 1); dv += __shfl_xor(dv, 1);
            sv += __shfl_xor(sv, 2); dv += __shfl_xor(dv, 2);
            sv += __shfl_xor(sv, 4); dv += __shfl_xor(dv, 4);
            int gr = rowbase + j;
            if ((lm & 7) == 0 && gr < Nn) {
                int hh = nt * 2 + (lm >> 3);
                as1[(size_t)gr * 8 + hh] = sv;
                ad1[(size_t)gr * 8 + hh] = dv;
            }
        }
    }
}

// ---------------------------------------------------------------------------
// Layer-1 fused softmax+aggregate + node2. One wave per dst node.
// PROVEN 16-lane map (lane = sub*16 + c4; 4 edge slots, lane owns 4 f32 ch
// as bf16x4 8B load), now unrolled 8-DEEP BRANCHLESS: slots cover i..i+28,
// masked slots clamp the csr index (re-reads a fetched line, zero traffic)
// and force e=-1e30 -> p=0 exactly. 8 outstanding gathers per lane (was 4)
// + no serial tail (mean degree ~17 previously paid 1-2 serialized tail
// iterations per wave).
// ---------------------------------------------------------------------------
__global__ __launch_bounds__(256, 4) void agg1n_k(const int* __restrict__ csr,
                                                  const int* __restrict__ rowptr,
                                                  const float* __restrict__ as1,
                                                  const float* __restrict__ ad1,
                                                  const __bf16* __restrict__ h1b,
                                                  const float* __restrict__ b1,
                                                  const float* __restrict__ W2,
                                                  const float* __restrict__ as2w,
                                                  const float* __restrict__ ad2w,
                                                  float* __restrict__ h2,
                                                  float* __restrict__ as2,
                                                  float* __restrict__ ad2, int Nn)
{
    __shared__ float W2s[640];
    for (int i = threadIdx.x; i < 640; i += 256) W2s[i] = W2[i];
    __syncthreads();   // before any early exit (divergent-barrier safety)

    int wid = (blockIdx.x * 256 + threadIdx.x) >> 6;
    if (wid >= Nn) return;
    int lane = threadIdx.x & 63;
    int sub = lane >> 4;        // edge slot 0..3
    int c4 = lane & 15;         // channel group (4 ch)
    int h = c4 >> 1;            // head
    float adv = ad1[(size_t)wid * 8 + h];
    int start = rowptr[wid];
    int len = rowptr[wid + 1] - start;
    float accp = 0.f;
    float4 accv = make_float4(0.f, 0.f, 0.f, 0.f);
    for (int i = sub; i < len; i += 32) {
        int idx = start + i;
        bool k1 = i + 4  < len, k2 = i + 8  < len, k3 = i + 12 < len;
        bool k4 = i + 16 < len, k5 = i + 20 < len, k6 = i + 24 < len, k7 = i + 28 < len;
        int s0 = csr[idx];
        int s1 = csr[idx + (k1 ? 4  : 0)];
        int s2 = csr[idx + (k2 ? 8  : 0)];
        int s3 = csr[idx + (k3 ? 12 : 0)];
        int s4 = csr[idx + (k4 ? 16 : 0)];
        int s5 = csr[idx + (k5 ? 20 : 0)];
        int s6 = csr[idx + (k6 ? 24 : 0)];
        int s7 = csr[idx + (k7 ? 28 : 0)];
        float e0 = as1[(size_t)s0 * 8 + h] + adv;
        float e1 = as1[(size_t)s1 * 8 + h] + adv;
        float e2 = as1[(size_t)s2 * 8 + h] + adv;
        float e3 = as1[(size_t)s3 * 8 + h] + adv;
        float e4 = as1[(size_t)s4 * 8 + h] + adv;
        float e5 = as1[(size_t)s5 * 8 + h] + adv;
        float e6 = as1[(size_t)s6 * 8 + h] + adv;
        float e7 = as1[(size_t)s7 * 8 + h] + adv;
        bf16x4 hv0 = *(const bf16x4*)(h1b + (size_t)s0 * 64 + c4 * 4);
        bf16x4 hv1 = *(const bf16x4*)(h1b + (size_t)s1 * 64 + c4 * 4);
        bf16x4 hv2 = *(const bf16x4*)(h1b + (size_t)s2 * 64 + c4 * 4);
        bf16x4 hv3 = *(const bf16x4*)(h1b + (size_t)s3 * 64 + c4 * 4);
        bf16x4 hv4 = *(const bf16x4*)(h1b + (size_t)s4 * 64 + c4 * 4);
        bf16x4 hv5 = *(const bf16x4*)(h1b + (size_t)s5 * 64 + c4 * 4);
        bf16x4 hv6 = *(const bf16x4*)(h1b + (size_t)s6 * 64 + c4 * 4);
        bf16x4 hv7 = *(const bf16x4*)(h1b + (size_t)s7 * 64 + c4 * 4);
        e0 = e0 > 0.f ? e0 : NEG * e0;
        e1 = e1 > 0.f ? e1 : NEG * e1;
        e2 = e2 > 0.f ? e2 : NEG * e2;
        e3 = e3 > 0.f ? e3 : NEG * e3;
        e4 = e4 > 0.f ? e4 : NEG * e4;
        e5 = e5 > 0.f ? e5 : NEG * e5;
        e6 = e6 > 0.f ? e6 : NEG * e6;
        e7 = e7 > 0.f ? e7 : NEG * e7;
        if (!k1) e1 = -1e30f;           // masked slots -> p = 0 exactly
        if (!k2) e2 = -1e30f;
        if (!k3) e3 = -1e30f;
        if (!k4) e4 = -1e30f;
        if (!k5) e5 = -1e30f;
        if (!k6) e6 = -1e30f;
        if (!k7) e7 = -1e30f;
        float p0 = __expf(e0), p1 = __expf(e1), p2 = __expf(e2), p3 = __expf(e3);
        float p4 = __expf(e4), p5 = __expf(e5), p6 = __expf(e6), p7 = __expf(e7);
        accp += ((p0 + p1) + (p2 + p3)) + ((p4 + p5) + (p6 + p7));
        accv.x += p0 * (float)hv0[0] + p1 * (float)hv1[0] + p2 * (float)hv2[0] + p3 * (float)hv3[0]
                + p4 * (float)hv4[0] + p5 * (float)hv5[0] + p6 * (float)hv6[0] + p7 * (float)hv7[0];
        accv.y += p0 * (float)hv0[1] + p1 * (float)hv1[1] + p2 * (float)hv2[1] + p3 * (float)hv3[1]
                + p4 * (float)hv4[1] + p5 * (float)hv5[1] + p6 * (float)hv6[1] + p7 * (float)hv7[1];
        accv.z += p0 * (float)hv0[2] + p1 * (float)hv1[2] + p2 * (float)hv2[2] + p3 * (float)hv3[2]
                + p4 * (float)hv4[2] + p5 * (float)hv5[2] + p6 * (float)hv6[2] + p7 * (float)hv7[2];
        accv.w += p0 * (float)hv0[3] + p1 * (float)hv1[3] + p2 * (float)hv2[3] + p3 * (float)hv3[3]
                + p4 * (float)hv4[3] + p5 * (float)hv5[3] + p6 * (float)hv6[3] + p7 * (float)hv7[3];
    }
    accp   += __shfl_xor(accp, 16);
    accv.x += __shfl_xor(accv.x, 16);
    accv.y += __shfl_xor(accv.y, 16);
    accv.z += __shfl_xor(accv.z, 16);
    accv.w += __shfl_xor(accv.w, 16);
    accp   += __shfl_xor(accp, 32);
    accv.x += __shfl_xor(accv.x, 32);
    accv.y += __shfl_xor(accv.y, 32);
    accv.z += __shfl_xor(accv.z, 32);
    accv.w += __shfl_xor(accv.w, 32);

    // ---- fused node2: bias + ELU + 64x10 matvec + layer-2 attn dots ----
    float inv = 1.f / (accp + 1e-16f);
    float4 b = *(const float4*)(b1 + c4 * 4);
    float g0 = accv.x * inv + b.x; g0 = g0 > 0.f ? g0 : expm1f(g0);
    float g1 = accv.y * inv + b.y; g1 = g1 > 0.f ? g1 : expm1f(g1);
    float g2 = accv.z * inv + b.z; g2 = g2 > 0.f ? g2 : expm1f(g2);
    float g3 = accv.w * inv + b.w; g3 = g3 > 0.f ? g3 : expm1f(g3);
    int k0 = c4 * 4;
    float aj[10];
#pragma unroll
    for (int j = 0; j < 10; ++j)
        aj[j] = g0 * W2s[(k0 + 0) * 10 + j] + g1 * W2s[(k0 + 1) * 10 + j]
              + g2 * W2s[(k0 + 2) * 10 + j] + g3 * W2s[(k0 + 3) * 10 + j];
#pragma unroll
    for (int m = 1; m <= 8; m <<= 1) {
#pragma unroll
        for (int j = 0; j < 10; ++j) aj[j] += __shfl_xor(aj[j], m);
    }
    if (lane == 0) {
        float s2 = 0.f, d2 = 0.f;
#pragma unroll
        for (int j = 0; j < 10; ++j) { s2 += aj[j] * as2w[j]; d2 += aj[j] * ad2w[j]; }
        *(float4*)(h2 + (size_t)wid * 16 + 0) = make_float4(aj[0], aj[1], aj[2], aj[3]);
        *(float4*)(h2 + (size_t)wid * 16 + 4) = make_float4(aj[4], aj[5], aj[6], aj[7]);
        h2[(size_t)wid * 16 + 8] = aj[8];
        h2[(size_t)wid * 16 + 9] = aj[9];
        as2[wid] = s2;
        ad2[wid] = d2;
    }
}

// ---------------------------------------------------------------------------
// Layer-2 fused softmax+aggregate + bias + log_softmax (round-4 proven form).
// ---------------------------------------------------------------------------
__global__ __launch_bounds__(256) void agg2l_k(const int* __restrict__ csr,
                                               const int* __restrict__ rowptr,
                                               const float* __restrict__ as2,
                                               const float* __restrict__ ad2,
                                               const float* __restrict__ h2,
                                               const float* __restrict__ b2,
                                               float* __restrict__ out, int Nn)
{
    int wid = (blockIdx.x * 256 + threadIdx.x) >> 6;
    if (wid >= Nn) return;
    int lane = threadIdx.x & 63;
    int sub = lane >> 4;
    int c = lane & 15;
    float adv = ad2[wid];
    int start = rowptr[wid];
    int len = rowptr[wid + 1] - start;
    float accp = 0.f, accv = 0.f;
    int i = sub;
    for (; i + 12 < len; i += 16) {
        int s0 = csr[start + i];
        int s1 = csr[start + i + 4];
        int s2 = csr[start + i + 8];
        int s3 = csr[start + i + 12];
        float e0 = as2[s0] + adv;
        float e1 = as2[s1] + adv;
        float e2 = as2[s2] + adv;
        float e3 = as2[s3] + adv;
        float v0 = (c < 10) ? h2[(size_t)s0 * 16 + c] : 0.f;
        float v1 = (c < 10) ? h2[(size_t)s1 * 16 + c] : 0.f;
        float v2 = (c < 10) ? h2[(size_t)s2 * 16 + c] : 0.f;
        float v3 = (c < 10) ? h2[(size_t)s3 * 16 + c] : 0.f;
        e0 = e0 > 0.f ? e0 : NEG * e0;
        e1 = e1 > 0.f ? e1 : NEG * e1;
        e2 = e2 > 0.f ? e2 : NEG * e2;
        e3 = e3 > 0.f ? e3 : NEG * e3;
        float p0 = __expf(e0), p1 = __expf(e1), p2 = __expf(e2), p3 = __expf(e3);
        accp += (p0 + p1) + (p2 + p3);
        accv += p0 * v0 + p1 * v1 + p2 * v2 + p3 * v3;
    }
    for (; i < len; i += 4) {
        int s0 = csr[start + i];
        float e0 = as2[s0] + adv;
        float v0 = (c < 10) ? h2[(size_t)s0 * 16 + c] : 0.f;
        e0 = e0 > 0.f ? e0 : NEG * e0;
        float p0 = __expf(e0);
        accp += p0;
        accv += p0 * v0;
    }
    accp += __shfl_xor(accp, 16);
    accv += __shfl_xor(accv, 16);
    accp += __shfl_xor(accp, 32);
    accv += __shfl_xor(accv, 32);

    // ---- fused bias + log_softmax over the 10 classes ----
    float z = (c < 10) ? accv / (accp + 1e-16f) + b2[c] : -1e30f;
    float m = z;
    m = fmaxf(m, __shfl_xor(m, 1));
    m = fmaxf(m, __shfl_xor(m, 2));
    m = fmaxf(m, __shfl_xor(m, 4));
    m = fmaxf(m, __shfl_xor(m, 8));
    float p = (c < 10) ? expf(z - m) : 0.f;
    p += __shfl_xor(p, 1);
    p += __shfl_xor(p, 2);
    p += __shfl_xor(p, 4);
    p += __shfl_xor(p, 8);
    float lse = m + logf(p);
    if (sub == 0 && c < 10)
        out[(size_t)wid * 10 + c] = z - lse;
}

// ---------------------------------------------------------------------------
extern "C" void kernel_launch(void* const* d_in, const int* in_sizes, int n_in,
                              void* d_out, int out_size, void* d_ws, size_t ws_size,
                              hipStream_t stream)
{
    const float* x     = (const float*)d_in[0];
    const float* W1    = (const float*)d_in[1];
    const float* asrc1 = (const float*)d_in[2];
    const float* adst1 = (const float*)d_in[3];
    const float* b1    = (const float*)d_in[4];
    const float* W2    = (const float*)d_in[5];
    const float* asrc2 = (const float*)d_in[6];
    const float* adst2 = (const float*)d_in[7];
    const float* b2    = (const float*)d_in[8];
    const int*   ei    = (const int*)d_in[9];
    float* out = (float*)d_out;

    int F  = in_sizes[1] / 64;       // 512
    int Nn = in_sizes[0] / F;        // 100000
    int E  = in_sizes[9] / 2;        // 1600000
    int Ep = E + Nn;
    int nb = (Nn + 1023) / 1024;

    float* f = (float*)d_ws;
    __bf16* w1b = (__bf16*)f;  f += 512 * 64 / 2;      // 64KB, 16B-aligned
    __bf16* h1b = (__bf16*)f;  f += (size_t)Nn * 32;   // Nn*64 bf16
    float* as1  = f;  f += (size_t)Nn * 8;
    float* ad1  = f;  f += (size_t)Nn * 8;
    float* h2   = f;  f += (size_t)Nn * 16;
    float* as2  = f;  f += Nn;
    float* ad2  = f;  f += Nn;
    int* ip = (int*)f;
    int* deg    = ip;  ip += Nn;
    int* rowptr = ip;  ip += Nn + 1;
    int* bsum   = ip;  ip += 256;
    int* rank   = ip;  ip += Ep;
    int* csr    = ip;  ip += Ep;

    int nbG = (Nn + 63) / 64;        // gemm blocks
    int nbS = (Ep + 255) / 256;      // scatter blocks

    // CSR histogram + W1 swizzle (fused, independent)
    hipMemsetAsync(deg, 0, (size_t)Nn * sizeof(int), stream);
    histw1_k<<<16 + nbS, 256, 0, stream>>>(ei, E, Nn, deg, rank, W1, w1b);

    // rowptr scan (2 launches: per-block sums, then fused top-scan + write)
    scan_a_k<<<nb, 256, 0, stream>>>(deg, Nn, bsum);
    scan_bc_k<<<nb, 256, 0, stream>>>(deg, Nn, bsum, nb, rowptr);

    // Layer-1 GEMM (+attn dots, bf16 h1 store) || atomic-free CSR scatter
    scatgemm_k<<<nbG + nbS, 256, 0, stream>>>(x, w1b, asrc1, adst1, h1b, as1, ad1,
                                              ei, E, rowptr, rank, csr, Nn, nbG);

    // Layer-1 aggregate + fused node2 (bias/ELU/GEMM2/attn2 dots)
    agg1n_k<<<(Nn + 3) / 4, 256, 0, stream>>>(csr, rowptr, as1, ad1, h1b,
                                              b1, W2, asrc2, adst2, h2, as2, ad2, Nn);

    // Layer-2 aggregate + fused bias + log_softmax
    agg2l_k<<<(Nn + 3) / 4, 256, 0, stream>>>(csr, rowptr, as2, ad2, h2, b2, out, Nn);
}

// Round 7
// 514.391 us; speedup vs baseline: 1.1411x; 1.1004x over previous
//
#include <hip/hip_runtime.h>
#include <math.h>

#define NEG 0.2f
#define CHP  4096      // edges per partition block
#define NPBK 512       // dst nodes per bucket
#define CAPB 12288     // bucket capacity in edges (mean ~8704, 38-sigma margin)

typedef __bf16 bf16x8 __attribute__((ext_vector_type(8)));
typedef __bf16 bf16x4 __attribute__((ext_vector_type(4)));
typedef float  f32x4  __attribute__((ext_vector_type(4)));

// ---------------------------------------------------------------------------
// part_k: fused W1 pre-swizzle (blocks 0..15) + bucketed edge partition.
// Partition blocks: LDS histogram over nbk (<=256) buckets -> one global
// atomicAdd per (block,bucket) reserves a contiguous range in the bucket's
// fixed-capacity region of ebuf -> packed u32 (dlocal<<17 | src) writes,
// contiguous per (block,bucket) => near-full 64B line utilization.
// Replaces 1.7M device-scope atomics with ~81K + LDS atomics.
// ---------------------------------------------------------------------------
__global__ __launch_bounds__(256) void part_k(const int* __restrict__ ei, int E, int Nn,
                                              int nbk,
                                              const float* __restrict__ W1,
                                              __bf16* __restrict__ W1b,
                                              int* __restrict__ gcur,
                                              int* __restrict__ ebuf)
{
    int t = threadIdx.x;
    if (blockIdx.x < 16) {
        // W1 pre-swizzle: slot i=(ch*4+lk)*64+n holds W1[ch*32+lk*8+j][n]
        int i = blockIdx.x * 256 + t;
        int n = i & 63;
        int k0 = (i >> 6) * 8;
#pragma unroll
        for (int j = 0; j < 8; ++j)
            W1b[(size_t)i * 8 + j] = (__bf16)W1[(size_t)(k0 + j) * 64 + n];
        return;
    }
    __shared__ int lh[256];
    int blk = (int)blockIdx.x - 16;
    int base = blk * CHP;
    int Ep = E + Nn;
    lh[t] = 0;
    __syncthreads();
    int d[16];
#pragma unroll
    for (int j = 0; j < 16; ++j) {
        int e = base + j * 256 + t;
        d[j] = (e < Ep) ? ((e < E) ? ei[E + e] : e - E) : -1;
        if (d[j] >= 0) atomicAdd(&lh[d[j] >> 9], 1);
    }
    __syncthreads();
    if (t < nbk) {
        int c = lh[t];
        lh[t] = (c > 0) ? atomicAdd(&gcur[t], c) : 0;   // global base for this block's range
    }
    __syncthreads();
#pragma unroll
    for (int j = 0; j < 16; ++j) {
        int e = base + j * 256 + t;
        if (e >= Ep) continue;
        int s = (e < E) ? ei[e] : e - E;
        int b = d[j] >> 9;
        int dl = d[j] & (NPBK - 1);
        int slot = atomicAdd(&lh[b], 1);
        if (slot < CAPB) ebuf[(size_t)b * CAPB + slot] = (dl << 17) | s;
    }
}

// ---------------------------------------------------------------------------
// bucket_k: one block per bucket. Builds the bucket's csr segment + rowptr
// entirely in LDS (LDS atomics only), then streams out coalesced.
// csrbase via redundant LDS scan of the 196 bucket counts (trivial).
// ---------------------------------------------------------------------------
__global__ __launch_bounds__(256) void bucket_k(const int* __restrict__ gcur, int nbk,
                                                int Nn, const int* __restrict__ ebuf,
                                                int* __restrict__ csr,
                                                int* __restrict__ rowptr)
{
    __shared__ int cscan[256];
    __shared__ int ldeg[NPBK];
    __shared__ int lsc[NPBK];
    __shared__ int lcsr[CAPB];      // 48 KB
    int t = threadIdx.x;
    int b = blockIdx.x;

    // exclusive base of this bucket in csr = prefix of bucket counts
    cscan[t] = (t < nbk) ? min(gcur[t], CAPB) : 0;
    __syncthreads();
    for (int off = 1; off < 256; off <<= 1) {
        int a = (t >= off) ? cscan[t - off] : 0;
        __syncthreads();
        cscan[t] += a;
        __syncthreads();
    }
    int csrbase = (b == 0) ? 0 : cscan[b - 1];
    int cnt = cscan[b] - csrbase;

    // local degree histogram
    ldeg[t] = 0; ldeg[t + 256] = 0;
    __syncthreads();
    const int* bp = ebuf + (size_t)b * CAPB;
    for (int i = t; i < cnt; i += 256)
        atomicAdd(&ldeg[bp[i] >> 17], 1);
    __syncthreads();

    // inclusive scan of 512 local degrees (2 elems/thread)
    lsc[t] = ldeg[t]; lsc[t + 256] = ldeg[t + 256];
    __syncthreads();
    for (int off = 1; off < NPBK; off <<= 1) {
        int a0 = (t >= off) ? lsc[t - off] : 0;
        int i1 = t + 256;
        int a1 = (i1 >= off) ? lsc[i1 - off] : 0;
        __syncthreads();
        lsc[t] += a0; lsc[i1] += a1;
        __syncthreads();
    }
    int excl0 = lsc[t] - ldeg[t];
    int excl1 = lsc[t + 256] - ldeg[t + 256];
    __syncthreads();
    ldeg[t] = excl0; ldeg[t + 256] = excl1;      // becomes the scatter cursor
    int g0 = b * NPBK + t, g1 = b * NPBK + t + 256;
    if (g0 < Nn) rowptr[g0] = csrbase + excl0;
    if (g1 < Nn) rowptr[g1] = csrbase + excl1;
    if (b == nbk - 1 && t == 0) rowptr[Nn] = cscan[nbk - 1];
    __syncthreads();

    // LDS scatter (bucket edges -> dst-sorted local csr)
    for (int i = t; i < cnt; i += 256) {
        int u = bp[i];                            // L2-hot re-read
        int slot = atomicAdd(&ldeg[u >> 17], 1);
        lcsr[slot] = u & 0x1FFFF;
    }
    __syncthreads();
    // coalesced stream-out
    for (int i = t; i < cnt; i += 256)
        csr[csrbase + i] = lcsr[i];
}

// ---------------------------------------------------------------------------
// K1: h1b[N,64](bf16) = x[N,512] @ W1[512,64] via bf16 MFMA (16x16x32), plus
// fused per-(node,head) attention dots from the f32 accumulators.
// C/D: col = lane&15, row = (lane>>4)*4 + reg (verified m89).
// ---------------------------------------------------------------------------
__global__ __launch_bounds__(256, 4) void gemm1a_k(const float* __restrict__ x,
                                                   const __bf16* __restrict__ W1b,
                                                   const float* __restrict__ asrc,
                                                   const float* __restrict__ adst,
                                                   __bf16* __restrict__ h1b,
                                                   float* __restrict__ as1,
                                                   float* __restrict__ ad1, int Nn)
{
    int t = threadIdx.x;
    int wave = t >> 6, lane = t & 63;
    int lm = lane & 15, lk = lane >> 4;
    int rowa = blockIdx.x * 64 + wave * 16 + lm;          // A: m = lane&15
    const float* xrow = x + (size_t)(rowa < Nn ? rowa : 0) * 512;
    f32x4 acc[4] = {};
#pragma unroll
    for (int ch = 0; ch < 16; ++ch) {
        float4 a0 = *(const float4*)(xrow + ch * 32 + lk * 8);
        float4 a1 = *(const float4*)(xrow + ch * 32 + lk * 8 + 4);
        bf16x8 af;
        af[0] = (__bf16)a0.x; af[1] = (__bf16)a0.y;
        af[2] = (__bf16)a0.z; af[3] = (__bf16)a0.w;
        af[4] = (__bf16)a1.x; af[5] = (__bf16)a1.y;
        af[6] = (__bf16)a1.z; af[7] = (__bf16)a1.w;
#pragma unroll
        for (int nt = 0; nt < 4; ++nt) {
            bf16x8 bf = *(const bf16x8*)(W1b + ((size_t)((ch * 4 + lk) * 64) + nt * 16 + lm) * 8);
            acc[nt] = __builtin_amdgcn_mfma_f32_16x16x32_bf16(af, bf, acc[nt], 0, 0, 0);
        }
    }
    int rowbase = blockIdx.x * 64 + wave * 16 + lk * 4;
#pragma unroll
    for (int nt = 0; nt < 4; ++nt) {
#pragma unroll
        for (int j = 0; j < 4; ++j) {
            int gr = rowbase + j;
            if (gr < Nn) h1b[(size_t)gr * 64 + nt * 16 + lm] = (__bf16)acc[nt][j];
        }
    }
#pragma unroll
    for (int nt = 0; nt < 4; ++nt) {
        float ws = asrc[nt * 16 + lm];
        float wd = adst[nt * 16 + lm];
#pragma unroll
        for (int j = 0; j < 4; ++j) {
            float sv = acc[nt][j] * ws;
            float dv = acc[nt][j] * wd;
            sv += __shfl_xor(sv, 1); dv += __shfl_xor(dv, 1);
            sv += __shfl_xor(sv, 2); dv += __shfl_xor(dv, 2);
            sv += __shfl_xor(sv, 4); dv += __shfl_xor(dv, 4);
            int gr = rowbase + j;
            if ((lm & 7) == 0 && gr < Nn) {
                int hh = nt * 2 + (lm >> 3);
                as1[(size_t)gr * 8 + hh] = sv;
                ad1[(size_t)gr * 8 + hh] = dv;
            }
        }
    }
}

// ---------------------------------------------------------------------------
// Layer-1 fused softmax+aggregate + node2 (r6 form: 16-lane map, 8-deep
// branchless unroll, bf16x4 gathers).
// ---------------------------------------------------------------------------
__global__ __launch_bounds__(256, 4) void agg1n_k(const int* __restrict__ csr,
                                                  const int* __restrict__ rowptr,
                                                  const float* __restrict__ as1,
                                                  const float* __restrict__ ad1,
                                                  const __bf16* __restrict__ h1b,
                                                  const float* __restrict__ b1,
                                                  const float* __restrict__ W2,
                                                  const float* __restrict__ as2w,
                                                  const float* __restrict__ ad2w,
                                                  float* __restrict__ h2,
                                                  float* __restrict__ as2,
                                                  float* __restrict__ ad2, int Nn)
{
    __shared__ float W2s[640];
    for (int i = threadIdx.x; i < 640; i += 256) W2s[i] = W2[i];
    __syncthreads();   // before any early exit (divergent-barrier safety)

    int wid = (blockIdx.x * 256 + threadIdx.x) >> 6;
    if (wid >= Nn) return;
    int lane = threadIdx.x & 63;
    int sub = lane >> 4;        // edge slot 0..3
    int c4 = lane & 15;         // channel group (4 ch)
    int h = c4 >> 1;            // head
    float adv = ad1[(size_t)wid * 8 + h];
    int start = rowptr[wid];
    int len = rowptr[wid + 1] - start;
    float accp = 0.f;
    float4 accv = make_float4(0.f, 0.f, 0.f, 0.f);
    for (int i = sub; i < len; i += 32) {
        int idx = start + i;
        bool k1 = i + 4  < len, k2 = i + 8  < len, k3 = i + 12 < len;
        bool k4 = i + 16 < len, k5 = i + 20 < len, k6 = i + 24 < len, k7 = i + 28 < len;
        int s0 = csr[idx];
        int s1 = csr[idx + (k1 ? 4  : 0)];
        int s2 = csr[idx + (k2 ? 8  : 0)];
        int s3 = csr[idx + (k3 ? 12 : 0)];
        int s4 = csr[idx + (k4 ? 16 : 0)];
        int s5 = csr[idx + (k5 ? 20 : 0)];
        int s6 = csr[idx + (k6 ? 24 : 0)];
        int s7 = csr[idx + (k7 ? 28 : 0)];
        float e0 = as1[(size_t)s0 * 8 + h] + adv;
        float e1 = as1[(size_t)s1 * 8 + h] + adv;
        float e2 = as1[(size_t)s2 * 8 + h] + adv;
        float e3 = as1[(size_t)s3 * 8 + h] + adv;
        float e4 = as1[(size_t)s4 * 8 + h] + adv;
        float e5 = as1[(size_t)s5 * 8 + h] + adv;
        float e6 = as1[(size_t)s6 * 8 + h] + adv;
        float e7 = as1[(size_t)s7 * 8 + h] + adv;
        bf16x4 hv0 = *(const bf16x4*)(h1b + (size_t)s0 * 64 + c4 * 4);
        bf16x4 hv1 = *(const bf16x4*)(h1b + (size_t)s1 * 64 + c4 * 4);
        bf16x4 hv2 = *(const bf16x4*)(h1b + (size_t)s2 * 64 + c4 * 4);
        bf16x4 hv3 = *(const bf16x4*)(h1b + (size_t)s3 * 64 + c4 * 4);
        bf16x4 hv4 = *(const bf16x4*)(h1b + (size_t)s4 * 64 + c4 * 4);
        bf16x4 hv5 = *(const bf16x4*)(h1b + (size_t)s5 * 64 + c4 * 4);
        bf16x4 hv6 = *(const bf16x4*)(h1b + (size_t)s6 * 64 + c4 * 4);
        bf16x4 hv7 = *(const bf16x4*)(h1b + (size_t)s7 * 64 + c4 * 4);
        e0 = e0 > 0.f ? e0 : NEG * e0;
        e1 = e1 > 0.f ? e1 : NEG * e1;
        e2 = e2 > 0.f ? e2 : NEG * e2;
        e3 = e3 > 0.f ? e3 : NEG * e3;
        e4 = e4 > 0.f ? e4 : NEG * e4;
        e5 = e5 > 0.f ? e5 : NEG * e5;
        e6 = e6 > 0.f ? e6 : NEG * e6;
        e7 = e7 > 0.f ? e7 : NEG * e7;
        if (!k1) e1 = -1e30f;           // masked slots -> p = 0 exactly
        if (!k2) e2 = -1e30f;
        if (!k3) e3 = -1e30f;
        if (!k4) e4 = -1e30f;
        if (!k5) e5 = -1e30f;
        if (!k6) e6 = -1e30f;
        if (!k7) e7 = -1e30f;
        float p0 = __expf(e0), p1 = __expf(e1), p2 = __expf(e2), p3 = __expf(e3);
        float p4 = __expf(e4), p5 = __expf(e5), p6 = __expf(e6), p7 = __expf(e7);
        accp += ((p0 + p1) + (p2 + p3)) + ((p4 + p5) + (p6 + p7));
        accv.x += p0 * (float)hv0[0] + p1 * (float)hv1[0] + p2 * (float)hv2[0] + p3 * (float)hv3[0]
                + p4 * (float)hv4[0] + p5 * (float)hv5[0] + p6 * (float)hv6[0] + p7 * (float)hv7[0];
        accv.y += p0 * (float)hv0[1] + p1 * (float)hv1[1] + p2 * (float)hv2[1] + p3 * (float)hv3[1]
                + p4 * (float)hv4[1] + p5 * (float)hv5[1] + p6 * (float)hv6[1] + p7 * (float)hv7[1];
        accv.z += p0 * (float)hv0[2] + p1 * (float)hv1[2] + p2 * (float)hv2[2] + p3 * (float)hv3[2]
                + p4 * (float)hv4[2] + p5 * (float)hv5[2] + p6 * (float)hv6[2] + p7 * (float)hv7[2];
        accv.w += p0 * (float)hv0[3] + p1 * (float)hv1[3] + p2 * (float)hv2[3] + p3 * (float)hv3[3]
                + p4 * (float)hv4[3] + p5 * (float)hv5[3] + p6 * (float)hv6[3] + p7 * (float)hv7[3];
    }
    accp   += __shfl_xor(accp, 16);
    accv.x += __shfl_xor(accv.x, 16);
    accv.y += __shfl_xor(accv.y, 16);
    accv.z += __shfl_xor(accv.z, 16);
    accv.w += __shfl_xor(accv.w, 16);
    accp   += __shfl_xor(accp, 32);
    accv.x += __shfl_xor(accv.x, 32);
    accv.y += __shfl_xor(accv.y, 32);
    accv.z += __shfl_xor(accv.z, 32);
    accv.w += __shfl_xor(accv.w, 32);

    // ---- fused node2: bias + ELU + 64x10 matvec + layer-2 attn dots ----
    float inv = 1.f / (accp + 1e-16f);
    float4 b = *(const float4*)(b1 + c4 * 4);
    float g0 = accv.x * inv + b.x; g0 = g0 > 0.f ? g0 : expm1f(g0);
    float g1 = accv.y * inv + b.y; g1 = g1 > 0.f ? g1 : expm1f(g1);
    float g2 = accv.z * inv + b.z; g2 = g2 > 0.f ? g2 : expm1f(g2);
    float g3 = accv.w * inv + b.w; g3 = g3 > 0.f ? g3 : expm1f(g3);
    int k0 = c4 * 4;
    float aj[10];
#pragma unroll
    for (int j = 0; j < 10; ++j)
        aj[j] = g0 * W2s[(k0 + 0) * 10 + j] + g1 * W2s[(k0 + 1) * 10 + j]
              + g2 * W2s[(k0 + 2) * 10 + j] + g3 * W2s[(k0 + 3) * 10 + j];
#pragma unroll
    for (int m = 1; m <= 8; m <<= 1) {
#pragma unroll
        for (int j = 0; j < 10; ++j) aj[j] += __shfl_xor(aj[j], m);
    }
    if (lane == 0) {
        float s2 = 0.f, d2 = 0.f;
#pragma unroll
        for (int j = 0; j < 10; ++j) { s2 += aj[j] * as2w[j]; d2 += aj[j] * ad2w[j]; }
        *(float4*)(h2 + (size_t)wid * 16 + 0) = make_float4(aj[0], aj[1], aj[2], aj[3]);
        *(float4*)(h2 + (size_t)wid * 16 + 4) = make_float4(aj[4], aj[5], aj[6], aj[7]);
        h2[(size_t)wid * 16 + 8] = aj[8];
        h2[(size_t)wid * 16 + 9] = aj[9];
        as2[wid] = s2;
        ad2[wid] = d2;
    }
}

// ---------------------------------------------------------------------------
// Layer-2 fused softmax+aggregate + bias + log_softmax (proven r4 form).
// ---------------------------------------------------------------------------
__global__ __launch_bounds__(256) void agg2l_k(const int* __restrict__ csr,
                                               const int* __restrict__ rowptr,
                                               const float* __restrict__ as2,
                                               const float* __restrict__ ad2,
                                               const float* __restrict__ h2,
                                               const float* __restrict__ b2,
                                               float* __restrict__ out, int Nn)
{
    int wid = (blockIdx.x * 256 + threadIdx.x) >> 6;
    if (wid >= Nn) return;
    int lane = threadIdx.x & 63;
    int sub = lane >> 4;
    int c = lane & 15;
    float adv = ad2[wid];
    int start = rowptr[wid];
    int len = rowptr[wid + 1] - start;
    float accp = 0.f, accv = 0.f;
    int i = sub;
    for (; i + 12 < len; i += 16) {
        int s0 = csr[start + i];
        int s1 = csr[start + i + 4];
        int s2 = csr[start + i + 8];
        int s3 = csr[start + i + 12];
        float e0 = as2[s0] + adv;
        float e1 = as2[s1] + adv;
        float e2 = as2[s2] + adv;
        float e3 = as2[s3] + adv;
        float v0 = (c < 10) ? h2[(size_t)s0 * 16 + c] : 0.f;
        float v1 = (c < 10) ? h2[(size_t)s1 * 16 + c] : 0.f;
        float v2 = (c < 10) ? h2[(size_t)s2 * 16 + c] : 0.f;
        float v3 = (c < 10) ? h2[(size_t)s3 * 16 + c] : 0.f;
        e0 = e0 > 0.f ? e0 : NEG * e0;
        e1 = e1 > 0.f ? e1 : NEG * e1;
        e2 = e2 > 0.f ? e2 : NEG * e2;
        e3 = e3 > 0.f ? e3 : NEG * e3;
        float p0 = __expf(e0), p1 = __expf(e1), p2 = __expf(e2), p3 = __expf(e3);
        accp += (p0 + p1) + (p2 + p3);
        accv += p0 * v0 + p1 * v1 + p2 * v2 + p3 * v3;
    }
    for (; i < len; i += 4) {
        int s0 = csr[start + i];
        float e0 = as2[s0] + adv;
        float v0 = (c < 10) ? h2[(size_t)s0 * 16 + c] : 0.f;
        e0 = e0 > 0.f ? e0 : NEG * e0;
        float p0 = __expf(e0);
        accp += p0;
        accv += p0 * v0;
    }
    accp += __shfl_xor(accp, 16);
    accv += __shfl_xor(accv, 16);
    accp += __shfl_xor(accp, 32);
    accv += __shfl_xor(accv, 32);

    float z = (c < 10) ? accv / (accp + 1e-16f) + b2[c] : -1e30f;
    float m = z;
    m = fmaxf(m, __shfl_xor(m, 1));
    m = fmaxf(m, __shfl_xor(m, 2));
    m = fmaxf(m, __shfl_xor(m, 4));
    m = fmaxf(m, __shfl_xor(m, 8));
    float p = (c < 10) ? expf(z - m) : 0.f;
    p += __shfl_xor(p, 1);
    p += __shfl_xor(p, 2);
    p += __shfl_xor(p, 4);
    p += __shfl_xor(p, 8);
    float lse = m + logf(p);
    if (sub == 0 && c < 10)
        out[(size_t)wid * 10 + c] = z - lse;
}

// ---------------------------------------------------------------------------
extern "C" void kernel_launch(void* const* d_in, const int* in_sizes, int n_in,
                              void* d_out, int out_size, void* d_ws, size_t ws_size,
                              hipStream_t stream)
{
    const float* x     = (const float*)d_in[0];
    const float* W1    = (const float*)d_in[1];
    const float* asrc1 = (const float*)d_in[2];
    const float* adst1 = (const float*)d_in[3];
    const float* b1    = (const float*)d_in[4];
    const float* W2    = (const float*)d_in[5];
    const float* asrc2 = (const float*)d_in[6];
    const float* adst2 = (const float*)d_in[7];
    const float* b2    = (const float*)d_in[8];
    const int*   ei    = (const int*)d_in[9];
    float* out = (float*)d_out;

    int F  = in_sizes[1] / 64;       // 512
    int Nn = in_sizes[0] / F;        // 100000
    int E  = in_sizes[9] / 2;        // 1600000
    int Ep = E + Nn;
    int nbk = (Nn + NPBK - 1) / NPBK;        // 196 buckets
    int nbP = (Ep + CHP - 1) / CHP;          // 416 partition blocks

    float* f = (float*)d_ws;
    __bf16* w1b = (__bf16*)f;  f += 512 * 64 / 2;      // 64KB, 16B-aligned
    __bf16* h1b = (__bf16*)f;  f += (size_t)Nn * 32;   // Nn*64 bf16
    float* as1  = f;  f += (size_t)Nn * 8;
    float* ad1  = f;  f += (size_t)Nn * 8;
    float* h2   = f;  f += (size_t)Nn * 16;
    float* as2  = f;  f += Nn;
    float* ad2  = f;  f += Nn;
    int* ip = (int*)f;
    int* rowptr = ip;  ip += Nn + 1;
    int* gcur   = ip;  ip += 256;
    int* ebuf   = ip;  ip += (size_t)nbk * CAPB;       // ~9.6 MB
    int* csr    = ip;  ip += Ep;

    // CSR build: bucketed partition -> per-bucket LDS build (all coalesced)
    hipMemsetAsync(gcur, 0, 256 * sizeof(int), stream);
    part_k<<<16 + nbP, 256, 0, stream>>>(ei, E, Nn, nbk, W1, w1b, gcur, ebuf);
    bucket_k<<<nbk, 256, 0, stream>>>(gcur, nbk, Nn, ebuf, csr, rowptr);

    // Layer-1 GEMM (+attn dots, bf16 h1 store)
    gemm1a_k<<<(Nn + 63) / 64, 256, 0, stream>>>(x, w1b, asrc1, adst1, h1b, as1, ad1, Nn);

    // Layer-1 aggregate + fused node2 (bias/ELU/GEMM2/attn2 dots)
    agg1n_k<<<(Nn + 3) / 4, 256, 0, stream>>>(csr, rowptr, as1, ad1, h1b,
                                              b1, W2, asrc2, adst2, h2, as2, ad2, Nn);

    // Layer-2 aggregate + fused bias + log_softmax
    agg2l_k<<<(Nn + 3) / 4, 256, 0, stream>>>(csr, rowptr, as2, ad2, h2, b2, out, Nn);
}

// Round 8
// 512.686 us; speedup vs baseline: 1.1449x; 1.0033x over previous
//
#include <hip/hip_runtime.h>
#include <math.h>

#define NEG 0.2f
#define CHP  4096      // edges per partition block
#define NPBK 512       // dst nodes per bucket
#define CAPB 12288     // bucket capacity in edges (mean ~8704, 38-sigma margin)

typedef __bf16 bf16x8 __attribute__((ext_vector_type(8)));
typedef __bf16 bf16x4 __attribute__((ext_vector_type(4)));
typedef float  f32x4  __attribute__((ext_vector_type(4)));

// ---------------------------------------------------------------------------
// part_k: fused W1 pre-swizzle (blocks 0..15) + bucketed edge partition.
// Partition blocks: LDS histogram over nbk (<=256) buckets -> one global
// atomicAdd per (block,bucket) reserves a contiguous range in the bucket's
// fixed-capacity region of ebuf -> packed u32 (dlocal<<17 | src) writes,
// contiguous per (block,bucket) => near-full 64B line utilization.
// ---------------------------------------------------------------------------
__global__ __launch_bounds__(256) void part_k(const int* __restrict__ ei, int E, int Nn,
                                              int nbk,
                                              const float* __restrict__ W1,
                                              __bf16* __restrict__ W1b,
                                              int* __restrict__ gcur,
                                              int* __restrict__ ebuf)
{
    int t = threadIdx.x;
    if (blockIdx.x < 16) {
        // W1 pre-swizzle: slot i=(ch*4+lk)*64+n holds W1[ch*32+lk*8+j][n]
        int i = blockIdx.x * 256 + t;
        int n = i & 63;
        int k0 = (i >> 6) * 8;
#pragma unroll
        for (int j = 0; j < 8; ++j)
            W1b[(size_t)i * 8 + j] = (__bf16)W1[(size_t)(k0 + j) * 64 + n];
        return;
    }
    __shared__ int lh[256];
    int blk = (int)blockIdx.x - 16;
    int base = blk * CHP;
    int Ep = E + Nn;
    lh[t] = 0;
    __syncthreads();
    int d[16];
#pragma unroll
    for (int j = 0; j < 16; ++j) {
        int e = base + j * 256 + t;
        d[j] = (e < Ep) ? ((e < E) ? ei[E + e] : e - E) : -1;
        if (d[j] >= 0) atomicAdd(&lh[d[j] >> 9], 1);
    }
    __syncthreads();
    if (t < nbk) {
        int c = lh[t];
        lh[t] = (c > 0) ? atomicAdd(&gcur[t], c) : 0;   // global base for this block's range
    }
    __syncthreads();
#pragma unroll
    for (int j = 0; j < 16; ++j) {
        int e = base + j * 256 + t;
        if (e >= Ep) continue;
        int s = (e < E) ? ei[e] : e - E;
        int b = d[j] >> 9;
        int dl = d[j] & (NPBK - 1);
        int slot = atomicAdd(&lh[b], 1);
        if (slot < CAPB) ebuf[(size_t)b * CAPB + slot] = (dl << 17) | s;
    }
}

// ---------------------------------------------------------------------------
// bucket_k: one block per bucket. Builds the bucket's csr segment + rowptr
// entirely in LDS (LDS atomics only), then streams out coalesced.
// ---------------------------------------------------------------------------
__global__ __launch_bounds__(256) void bucket_k(const int* __restrict__ gcur, int nbk,
                                                int Nn, const int* __restrict__ ebuf,
                                                int* __restrict__ csr,
                                                int* __restrict__ rowptr)
{
    __shared__ int cscan[256];
    __shared__ int ldeg[NPBK];
    __shared__ int lsc[NPBK];
    __shared__ int lcsr[CAPB];      // 48 KB
    int t = threadIdx.x;
    int b = blockIdx.x;

    // exclusive base of this bucket in csr = prefix of bucket counts
    cscan[t] = (t < nbk) ? min(gcur[t], CAPB) : 0;
    __syncthreads();
    for (int off = 1; off < 256; off <<= 1) {
        int a = (t >= off) ? cscan[t - off] : 0;
        __syncthreads();
        cscan[t] += a;
        __syncthreads();
    }
    int csrbase = (b == 0) ? 0 : cscan[b - 1];
    int cnt = cscan[b] - csrbase;

    // local degree histogram
    ldeg[t] = 0; ldeg[t + 256] = 0;
    __syncthreads();
    const int* bp = ebuf + (size_t)b * CAPB;
    for (int i = t; i < cnt; i += 256)
        atomicAdd(&ldeg[bp[i] >> 17], 1);
    __syncthreads();

    // inclusive scan of 512 local degrees (2 elems/thread)
    lsc[t] = ldeg[t]; lsc[t + 256] = ldeg[t + 256];
    __syncthreads();
    for (int off = 1; off < NPBK; off <<= 1) {
        int a0 = (t >= off) ? lsc[t - off] : 0;
        int i1 = t + 256;
        int a1 = (i1 >= off) ? lsc[i1 - off] : 0;
        __syncthreads();
        lsc[t] += a0; lsc[i1] += a1;
        __syncthreads();
    }
    int excl0 = lsc[t] - ldeg[t];
    int excl1 = lsc[t + 256] - ldeg[t + 256];
    __syncthreads();
    ldeg[t] = excl0; ldeg[t + 256] = excl1;      // becomes the scatter cursor
    int g0 = b * NPBK + t, g1 = b * NPBK + t + 256;
    if (g0 < Nn) rowptr[g0] = csrbase + excl0;
    if (g1 < Nn) rowptr[g1] = csrbase + excl1;
    if (b == nbk - 1 && t == 0) rowptr[Nn] = cscan[nbk - 1];
    __syncthreads();

    // LDS scatter (bucket edges -> dst-sorted local csr)
    for (int i = t; i < cnt; i += 256) {
        int u = bp[i];                            // L2-hot re-read
        int slot = atomicAdd(&ldeg[u >> 17], 1);
        lcsr[slot] = u & 0x1FFFF;
    }
    __syncthreads();
    // coalesced stream-out
    for (int i = t; i < cnt; i += 256)
        csr[csrbase + i] = lcsr[i];
}

// ---------------------------------------------------------------------------
// K1: h1b[N,64](bf16) = x[N,512] @ W1[512,64] via bf16 MFMA (16x16x32), plus
// fused per-(node,head) attention dots from the f32 accumulators.
// C/D: col = lane&15, row = (lane>>4)*4 + reg (verified m89).
// ---------------------------------------------------------------------------
__global__ __launch_bounds__(256, 4) void gemm1a_k(const float* __restrict__ x,
                                                   const __bf16* __restrict__ W1b,
                                                   const float* __restrict__ asrc,
                                                   const float* __restrict__ adst,
                                                   __bf16* __restrict__ h1b,
                                                   float* __restrict__ as1,
                                                   float* __restrict__ ad1, int Nn)
{
    int t = threadIdx.x;
    int wave = t >> 6, lane = t & 63;
    int lm = lane & 15, lk = lane >> 4;
    int rowa = blockIdx.x * 64 + wave * 16 + lm;          // A: m = lane&15
    const float* xrow = x + (size_t)(rowa < Nn ? rowa : 0) * 512;
    f32x4 acc[4] = {};
#pragma unroll
    for (int ch = 0; ch < 16; ++ch) {
        float4 a0 = *(const float4*)(xrow + ch * 32 + lk * 8);
        float4 a1 = *(const float4*)(xrow + ch * 32 + lk * 8 + 4);
        bf16x8 af;
        af[0] = (__bf16)a0.x; af[1] = (__bf16)a0.y;
        af[2] = (__bf16)a0.z; af[3] = (__bf16)a0.w;
        af[4] = (__bf16)a1.x; af[5] = (__bf16)a1.y;
        af[6] = (__bf16)a1.z; af[7] = (__bf16)a1.w;
#pragma unroll
        for (int nt = 0; nt < 4; ++nt) {
            bf16x8 bf = *(const bf16x8*)(W1b + ((size_t)((ch * 4 + lk) * 64) + nt * 16 + lm) * 8);
            acc[nt] = __builtin_amdgcn_mfma_f32_16x16x32_bf16(af, bf, acc[nt], 0, 0, 0);
        }
    }
    int rowbase = blockIdx.x * 64 + wave * 16 + lk * 4;
#pragma unroll
    for (int nt = 0; nt < 4; ++nt) {
#pragma unroll
        for (int j = 0; j < 4; ++j) {
            int gr = rowbase + j;
            if (gr < Nn) h1b[(size_t)gr * 64 + nt * 16 + lm] = (__bf16)acc[nt][j];
        }
    }
#pragma unroll
    for (int nt = 0; nt < 4; ++nt) {
        float ws = asrc[nt * 16 + lm];
        float wd = adst[nt * 16 + lm];
#pragma unroll
        for (int j = 0; j < 4; ++j) {
            float sv = acc[nt][j] * ws;
            float dv = acc[nt][j] * wd;
            sv += __shfl_xor(sv, 1); dv += __shfl_xor(dv, 1);
            sv += __shfl_xor(sv, 2); dv += __shfl_xor(dv, 2);
            sv += __shfl_xor(sv, 4); dv += __shfl_xor(dv, 4);
            int gr = rowbase + j;
            if ((lm & 7) == 0 && gr < Nn) {
                int hh = nt * 2 + (lm >> 3);
                as1[(size_t)gr * 8 + hh] = sv;
                ad1[(size_t)gr * 8 + hh] = dv;
            }
        }
    }
}

// ---------------------------------------------------------------------------
// Layer-1 fused softmax+aggregate + node2 (r6 form: 16-lane map, 8-deep
// branchless unroll, bf16x4 gathers). Epilogue now packs the layer-2 src
// attention dot into h2 row slot 10 (same 64B line as the class vector) so
// agg2l needs ONE gather line per edge.
// ---------------------------------------------------------------------------
__global__ __launch_bounds__(256, 4) void agg1n_k(const int* __restrict__ csr,
                                                  const int* __restrict__ rowptr,
                                                  const float* __restrict__ as1,
                                                  const float* __restrict__ ad1,
                                                  const __bf16* __restrict__ h1b,
                                                  const float* __restrict__ b1,
                                                  const float* __restrict__ W2,
                                                  const float* __restrict__ as2w,
                                                  const float* __restrict__ ad2w,
                                                  float* __restrict__ h2,
                                                  float* __restrict__ ad2, int Nn)
{
    __shared__ float W2s[640];
    for (int i = threadIdx.x; i < 640; i += 256) W2s[i] = W2[i];
    __syncthreads();   // before any early exit (divergent-barrier safety)

    int wid = (blockIdx.x * 256 + threadIdx.x) >> 6;
    if (wid >= Nn) return;
    int lane = threadIdx.x & 63;
    int sub = lane >> 4;        // edge slot 0..3
    int c4 = lane & 15;         // channel group (4 ch)
    int h = c4 >> 1;            // head
    float adv = ad1[(size_t)wid * 8 + h];
    int start = rowptr[wid];
    int len = rowptr[wid + 1] - start;
    float accp = 0.f;
    float4 accv = make_float4(0.f, 0.f, 0.f, 0.f);
    for (int i = sub; i < len; i += 32) {
        int idx = start + i;
        bool k1 = i + 4  < len, k2 = i + 8  < len, k3 = i + 12 < len;
        bool k4 = i + 16 < len, k5 = i + 20 < len, k6 = i + 24 < len, k7 = i + 28 < len;
        int s0 = csr[idx];
        int s1 = csr[idx + (k1 ? 4  : 0)];
        int s2 = csr[idx + (k2 ? 8  : 0)];
        int s3 = csr[idx + (k3 ? 12 : 0)];
        int s4 = csr[idx + (k4 ? 16 : 0)];
        int s5 = csr[idx + (k5 ? 20 : 0)];
        int s6 = csr[idx + (k6 ? 24 : 0)];
        int s7 = csr[idx + (k7 ? 28 : 0)];
        float e0 = as1[(size_t)s0 * 8 + h] + adv;
        float e1 = as1[(size_t)s1 * 8 + h] + adv;
        float e2 = as1[(size_t)s2 * 8 + h] + adv;
        float e3 = as1[(size_t)s3 * 8 + h] + adv;
        float e4 = as1[(size_t)s4 * 8 + h] + adv;
        float e5 = as1[(size_t)s5 * 8 + h] + adv;
        float e6 = as1[(size_t)s6 * 8 + h] + adv;
        float e7 = as1[(size_t)s7 * 8 + h] + adv;
        bf16x4 hv0 = *(const bf16x4*)(h1b + (size_t)s0 * 64 + c4 * 4);
        bf16x4 hv1 = *(const bf16x4*)(h1b + (size_t)s1 * 64 + c4 * 4);
        bf16x4 hv2 = *(const bf16x4*)(h1b + (size_t)s2 * 64 + c4 * 4);
        bf16x4 hv3 = *(const bf16x4*)(h1b + (size_t)s3 * 64 + c4 * 4);
        bf16x4 hv4 = *(const bf16x4*)(h1b + (size_t)s4 * 64 + c4 * 4);
        bf16x4 hv5 = *(const bf16x4*)(h1b + (size_t)s5 * 64 + c4 * 4);
        bf16x4 hv6 = *(const bf16x4*)(h1b + (size_t)s6 * 64 + c4 * 4);
        bf16x4 hv7 = *(const bf16x4*)(h1b + (size_t)s7 * 64 + c4 * 4);
        e0 = e0 > 0.f ? e0 : NEG * e0;
        e1 = e1 > 0.f ? e1 : NEG * e1;
        e2 = e2 > 0.f ? e2 : NEG * e2;
        e3 = e3 > 0.f ? e3 : NEG * e3;
        e4 = e4 > 0.f ? e4 : NEG * e4;
        e5 = e5 > 0.f ? e5 : NEG * e5;
        e6 = e6 > 0.f ? e6 : NEG * e6;
        e7 = e7 > 0.f ? e7 : NEG * e7;
        if (!k1) e1 = -1e30f;           // masked slots -> p = 0 exactly
        if (!k2) e2 = -1e30f;
        if (!k3) e3 = -1e30f;
        if (!k4) e4 = -1e30f;
        if (!k5) e5 = -1e30f;
        if (!k6) e6 = -1e30f;
        if (!k7) e7 = -1e30f;
        float p0 = __expf(e0), p1 = __expf(e1), p2 = __expf(e2), p3 = __expf(e3);
        float p4 = __expf(e4), p5 = __expf(e5), p6 = __expf(e6), p7 = __expf(e7);
        accp += ((p0 + p1) + (p2 + p3)) + ((p4 + p5) + (p6 + p7));
        accv.x += p0 * (float)hv0[0] + p1 * (float)hv1[0] + p2 * (float)hv2[0] + p3 * (float)hv3[0]
                + p4 * (float)hv4[0] + p5 * (float)hv5[0] + p6 * (float)hv6[0] + p7 * (float)hv7[0];
        accv.y += p0 * (float)hv0[1] + p1 * (float)hv1[1] + p2 * (float)hv2[1] + p3 * (float)hv3[1]
                + p4 * (float)hv4[1] + p5 * (float)hv5[1] + p6 * (float)hv6[1] + p7 * (float)hv7[1];
        accv.z += p0 * (float)hv0[2] + p1 * (float)hv1[2] + p2 * (float)hv2[2] + p3 * (float)hv3[2]
                + p4 * (float)hv4[2] + p5 * (float)hv5[2] + p6 * (float)hv6[2] + p7 * (float)hv7[2];
        accv.w += p0 * (float)hv0[3] + p1 * (float)hv1[3] + p2 * (float)hv2[3] + p3 * (float)hv3[3]
                + p4 * (float)hv4[3] + p5 * (float)hv5[3] + p6 * (float)hv6[3] + p7 * (float)hv7[3];
    }
    accp   += __shfl_xor(accp, 16);
    accv.x += __shfl_xor(accv.x, 16);
    accv.y += __shfl_xor(accv.y, 16);
    accv.z += __shfl_xor(accv.z, 16);
    accv.w += __shfl_xor(accv.w, 16);
    accp   += __shfl_xor(accp, 32);
    accv.x += __shfl_xor(accv.x, 32);
    accv.y += __shfl_xor(accv.y, 32);
    accv.z += __shfl_xor(accv.z, 32);
    accv.w += __shfl_xor(accv.w, 32);

    // ---- fused node2: bias + ELU + 64x10 matvec + layer-2 attn dots ----
    float inv = 1.f / (accp + 1e-16f);
    float4 b = *(const float4*)(b1 + c4 * 4);
    float g0 = accv.x * inv + b.x; g0 = g0 > 0.f ? g0 : expm1f(g0);
    float g1 = accv.y * inv + b.y; g1 = g1 > 0.f ? g1 : expm1f(g1);
    float g2 = accv.z * inv + b.z; g2 = g2 > 0.f ? g2 : expm1f(g2);
    float g3 = accv.w * inv + b.w; g3 = g3 > 0.f ? g3 : expm1f(g3);
    int k0 = c4 * 4;
    float aj[10];
#pragma unroll
    for (int j = 0; j < 10; ++j)
        aj[j] = g0 * W2s[(k0 + 0) * 10 + j] + g1 * W2s[(k0 + 1) * 10 + j]
              + g2 * W2s[(k0 + 2) * 10 + j] + g3 * W2s[(k0 + 3) * 10 + j];
#pragma unroll
    for (int m = 1; m <= 8; m <<= 1) {
#pragma unroll
        for (int j = 0; j < 10; ++j) aj[j] += __shfl_xor(aj[j], m);
    }
    if (lane == 0) {
        float s2 = 0.f, d2 = 0.f;
#pragma unroll
        for (int j = 0; j < 10; ++j) { s2 += aj[j] * as2w[j]; d2 += aj[j] * ad2w[j]; }
        *(float4*)(h2 + (size_t)wid * 16 + 0) = make_float4(aj[0], aj[1], aj[2], aj[3]);
        *(float4*)(h2 + (size_t)wid * 16 + 4) = make_float4(aj[4], aj[5], aj[6], aj[7]);
        h2[(size_t)wid * 16 + 8]  = aj[8];
        h2[(size_t)wid * 16 + 9]  = aj[9];
        h2[(size_t)wid * 16 + 10] = s2;     // packed: as2 lives in the same line
        ad2[wid] = d2;
    }
}

// ---------------------------------------------------------------------------
// Layer-2 fused softmax+aggregate + bias + log_softmax. One wave per dst.
// PACKED gather: lane c loads h2row[c]; slot's attention logit comes from
// lane sub*16+10 via one shfl -> exactly ONE 64B line per edge (was 2).
// ---------------------------------------------------------------------------
__global__ __launch_bounds__(256) void agg2l_k(const int* __restrict__ csr,
                                               const int* __restrict__ rowptr,
                                               const float* __restrict__ ad2,
                                               const float* __restrict__ h2,
                                               const float* __restrict__ b2,
                                               float* __restrict__ out, int Nn)
{
    int wid = (blockIdx.x * 256 + threadIdx.x) >> 6;
    if (wid >= Nn) return;
    int lane = threadIdx.x & 63;
    int sub = lane >> 4;
    int c = lane & 15;
    int src10 = (lane & 48) + 10;        // lane holding as2 for this slot
    float adv = ad2[wid];
    int start = rowptr[wid];
    int len = rowptr[wid + 1] - start;
    float accp = 0.f, accv = 0.f;
    int i = sub;
    for (; i + 12 < len; i += 16) {
        int s0 = csr[start + i];
        int s1 = csr[start + i + 4];
        int s2 = csr[start + i + 8];
        int s3 = csr[start + i + 12];
        float v0 = h2[(size_t)s0 * 16 + c];
        float v1 = h2[(size_t)s1 * 16 + c];
        float v2 = h2[(size_t)s2 * 16 + c];
        float v3 = h2[(size_t)s3 * 16 + c];
        float e0 = __shfl(v0, src10) + adv;
        float e1 = __shfl(v1, src10) + adv;
        float e2 = __shfl(v2, src10) + adv;
        float e3 = __shfl(v3, src10) + adv;
        float w0 = (c < 10) ? v0 : 0.f;
        float w1 = (c < 10) ? v1 : 0.f;
        float w2 = (c < 10) ? v2 : 0.f;
        float w3 = (c < 10) ? v3 : 0.f;
        e0 = e0 > 0.f ? e0 : NEG * e0;
        e1 = e1 > 0.f ? e1 : NEG * e1;
        e2 = e2 > 0.f ? e2 : NEG * e2;
        e3 = e3 > 0.f ? e3 : NEG * e3;
        float p0 = __expf(e0), p1 = __expf(e1), p2 = __expf(e2), p3 = __expf(e3);
        accp += (p0 + p1) + (p2 + p3);
        accv += p0 * w0 + p1 * w1 + p2 * w2 + p3 * w3;
    }
    for (; i < len; i += 4) {
        int s0 = csr[start + i];
        float v0 = h2[(size_t)s0 * 16 + c];
        float e0 = __shfl(v0, src10) + adv;
        float w0 = (c < 10) ? v0 : 0.f;
        e0 = e0 > 0.f ? e0 : NEG * e0;
        float p0 = __expf(e0);
        accp += p0;
        accv += p0 * w0;
    }
    accp += __shfl_xor(accp, 16);
    accv += __shfl_xor(accv, 16);
    accp += __shfl_xor(accp, 32);
    accv += __shfl_xor(accv, 32);

    float z = (c < 10) ? accv / (accp + 1e-16f) + b2[c] : -1e30f;
    float m = z;
    m = fmaxf(m, __shfl_xor(m, 1));
    m = fmaxf(m, __shfl_xor(m, 2));
    m = fmaxf(m, __shfl_xor(m, 4));
    m = fmaxf(m, __shfl_xor(m, 8));
    float p = (c < 10) ? expf(z - m) : 0.f;
    p += __shfl_xor(p, 1);
    p += __shfl_xor(p, 2);
    p += __shfl_xor(p, 4);
    p += __shfl_xor(p, 8);
    float lse = m + logf(p);
    if (sub == 0 && c < 10)
        out[(size_t)wid * 10 + c] = z - lse;
}

// ---------------------------------------------------------------------------
extern "C" void kernel_launch(void* const* d_in, const int* in_sizes, int n_in,
                              void* d_out, int out_size, void* d_ws, size_t ws_size,
                              hipStream_t stream)
{
    const float* x     = (const float*)d_in[0];
    const float* W1    = (const float*)d_in[1];
    const float* asrc1 = (const float*)d_in[2];
    const float* adst1 = (const float*)d_in[3];
    const float* b1    = (const float*)d_in[4];
    const float* W2    = (const float*)d_in[5];
    const float* asrc2 = (const float*)d_in[6];
    const float* adst2 = (const float*)d_in[7];
    const float* b2    = (const float*)d_in[8];
    const int*   ei    = (const int*)d_in[9];
    float* out = (float*)d_out;

    int F  = in_sizes[1] / 64;       // 512
    int Nn = in_sizes[0] / F;        // 100000
    int E  = in_sizes[9] / 2;        // 1600000
    int Ep = E + Nn;
    int nbk = (Nn + NPBK - 1) / NPBK;        // 196 buckets
    int nbP = (Ep + CHP - 1) / CHP;          // 416 partition blocks

    float* f = (float*)d_ws;
    __bf16* w1b = (__bf16*)f;  f += 512 * 64 / 2;      // 64KB, 16B-aligned
    __bf16* h1b = (__bf16*)f;  f += (size_t)Nn * 32;   // Nn*64 bf16
    float* as1  = f;  f += (size_t)Nn * 8;
    float* ad1  = f;  f += (size_t)Nn * 8;
    float* h2   = f;  f += (size_t)Nn * 16;            // row: 10 classes + as2@slot10
    float* ad2  = f;  f += Nn;
    int* ip = (int*)f;
    int* rowptr = ip;  ip += Nn + 1;
    int* gcur   = ip;  ip += 256;
    int* ebuf   = ip;  ip += (size_t)nbk * CAPB;       // ~9.6 MB
    int* csr    = ip;  ip += Ep;

    // CSR build: bucketed partition -> per-bucket LDS build (all coalesced)
    hipMemsetAsync(gcur, 0, 256 * sizeof(int), stream);
    part_k<<<16 + nbP, 256, 0, stream>>>(ei, E, Nn, nbk, W1, w1b, gcur, ebuf);
    bucket_k<<<nbk, 256, 0, stream>>>(gcur, nbk, Nn, ebuf, csr, rowptr);

    // Layer-1 GEMM (+attn dots, bf16 h1 store)
    gemm1a_k<<<(Nn + 63) / 64, 256, 0, stream>>>(x, w1b, asrc1, adst1, h1b, as1, ad1, Nn);

    // Layer-1 aggregate + fused node2 (bias/ELU/GEMM2/attn2 dots, packed h2)
    agg1n_k<<<(Nn + 3) / 4, 256, 0, stream>>>(csr, rowptr, as1, ad1, h1b,
                                              b1, W2, asrc2, adst2, h2, ad2, Nn);

    // Layer-2 aggregate + fused bias + log_softmax (one line per edge)
    agg2l_k<<<(Nn + 3) / 4, 256, 0, stream>>>(csr, rowptr, ad2, h2, b2, out, Nn);
}

// Round 9
// 509.312 us; speedup vs baseline: 1.1525x; 1.0066x over previous
//
#include <hip/hip_runtime.h>
#include <math.h>

#define NEG 0.2f
#define CHP  4096      // edges per partition block
#define NPBK 512       // dst nodes per bucket
#define CAPB 12288     // bucket capacity in edges (mean ~8704, 38-sigma margin)

typedef __bf16 bf16x8 __attribute__((ext_vector_type(8)));
typedef __bf16 bf16x4 __attribute__((ext_vector_type(4)));
typedef float  f32x4  __attribute__((ext_vector_type(4)));

// ---------------------------------------------------------------------------
// part_k: fused W1 pre-swizzle (blocks 0..15) + bucketed edge partition.
// ---------------------------------------------------------------------------
__global__ __launch_bounds__(256) void part_k(const int* __restrict__ ei, int E, int Nn,
                                              int nbk,
                                              const float* __restrict__ W1,
                                              __bf16* __restrict__ W1b,
                                              int* __restrict__ gcur,
                                              int* __restrict__ ebuf)
{
    int t = threadIdx.x;
    if (blockIdx.x < 16) {
        // W1 pre-swizzle: slot i=(ch*4+lk)*64+n holds W1[ch*32+lk*8+j][n]
        int i = blockIdx.x * 256 + t;
        int n = i & 63;
        int k0 = (i >> 6) * 8;
#pragma unroll
        for (int j = 0; j < 8; ++j)
            W1b[(size_t)i * 8 + j] = (__bf16)W1[(size_t)(k0 + j) * 64 + n];
        return;
    }
    __shared__ int lh[256];
    int blk = (int)blockIdx.x - 16;
    int base = blk * CHP;
    int Ep = E + Nn;
    lh[t] = 0;
    __syncthreads();
    int d[16];
#pragma unroll
    for (int j = 0; j < 16; ++j) {
        int e = base + j * 256 + t;
        d[j] = (e < Ep) ? ((e < E) ? ei[E + e] : e - E) : -1;
        if (d[j] >= 0) atomicAdd(&lh[d[j] >> 9], 1);
    }
    __syncthreads();
    if (t < nbk) {
        int c = lh[t];
        lh[t] = (c > 0) ? atomicAdd(&gcur[t], c) : 0;   // global base for this block's range
    }
    __syncthreads();
#pragma unroll
    for (int j = 0; j < 16; ++j) {
        int e = base + j * 256 + t;
        if (e >= Ep) continue;
        int s = (e < E) ? ei[e] : e - E;
        int b = d[j] >> 9;
        int dl = d[j] & (NPBK - 1);
        int slot = atomicAdd(&lh[b], 1);
        if (slot < CAPB) ebuf[(size_t)b * CAPB + slot] = (dl << 17) | s;
    }
}

// ---------------------------------------------------------------------------
// bucket_k: one block per bucket. Builds the bucket's csr segment + rowptr
// entirely in LDS (LDS atomics only), then streams out coalesced.
// ---------------------------------------------------------------------------
__global__ __launch_bounds__(256) void bucket_k(const int* __restrict__ gcur, int nbk,
                                                int Nn, const int* __restrict__ ebuf,
                                                int* __restrict__ csr,
                                                int* __restrict__ rowptr)
{
    __shared__ int cscan[256];
    __shared__ int ldeg[NPBK];
    __shared__ int lsc[NPBK];
    __shared__ int lcsr[CAPB];      // 48 KB
    int t = threadIdx.x;
    int b = blockIdx.x;

    // exclusive base of this bucket in csr = prefix of bucket counts
    cscan[t] = (t < nbk) ? min(gcur[t], CAPB) : 0;
    __syncthreads();
    for (int off = 1; off < 256; off <<= 1) {
        int a = (t >= off) ? cscan[t - off] : 0;
        __syncthreads();
        cscan[t] += a;
        __syncthreads();
    }
    int csrbase = (b == 0) ? 0 : cscan[b - 1];
    int cnt = cscan[b] - csrbase;

    // local degree histogram
    ldeg[t] = 0; ldeg[t + 256] = 0;
    __syncthreads();
    const int* bp = ebuf + (size_t)b * CAPB;
    for (int i = t; i < cnt; i += 256)
        atomicAdd(&ldeg[bp[i] >> 17], 1);
    __syncthreads();

    // inclusive scan of 512 local degrees (2 elems/thread)
    lsc[t] = ldeg[t]; lsc[t + 256] = ldeg[t + 256];
    __syncthreads();
    for (int off = 1; off < NPBK; off <<= 1) {
        int a0 = (t >= off) ? lsc[t - off] : 0;
        int i1 = t + 256;
        int a1 = (i1 >= off) ? lsc[i1 - off] : 0;
        __syncthreads();
        lsc[t] += a0; lsc[i1] += a1;
        __syncthreads();
    }
    int excl0 = lsc[t] - ldeg[t];
    int excl1 = lsc[t + 256] - ldeg[t + 256];
    __syncthreads();
    ldeg[t] = excl0; ldeg[t + 256] = excl1;      // becomes the scatter cursor
    int g0 = b * NPBK + t, g1 = b * NPBK + t + 256;
    if (g0 < Nn) rowptr[g0] = csrbase + excl0;
    if (g1 < Nn) rowptr[g1] = csrbase + excl1;
    if (b == nbk - 1 && t == 0) rowptr[Nn] = cscan[nbk - 1];
    __syncthreads();

    // LDS scatter (bucket edges -> dst-sorted local csr)
    for (int i = t; i < cnt; i += 256) {
        int u = bp[i];                            // L2-hot re-read
        int slot = atomicAdd(&ldeg[u >> 17], 1);
        lcsr[slot] = u & 0x1FFFF;
    }
    __syncthreads();
    // coalesced stream-out
    for (int i = t; i < cnt; i += 256)
        csr[csrbase + i] = lcsr[i];
}

// ---------------------------------------------------------------------------
// K1: h1b[N,64](bf16) = x[N,512] @ W1[512,64] via bf16 MFMA (16x16x32), plus
// fused per-(node,head) attention dots from the f32 accumulators.
// C/D: col = lane&15, row = (lane>>4)*4 + reg (verified m89).
// ---------------------------------------------------------------------------
__global__ __launch_bounds__(256, 4) void gemm1a_k(const float* __restrict__ x,
                                                   const __bf16* __restrict__ W1b,
                                                   const float* __restrict__ asrc,
                                                   const float* __restrict__ adst,
                                                   __bf16* __restrict__ h1b,
                                                   float* __restrict__ as1,
                                                   float* __restrict__ ad1, int Nn)
{
    int t = threadIdx.x;
    int wave = t >> 6, lane = t & 63;
    int lm = lane & 15, lk = lane >> 4;
    int rowa = blockIdx.x * 64 + wave * 16 + lm;          // A: m = lane&15
    const float* xrow = x + (size_t)(rowa < Nn ? rowa : 0) * 512;
    f32x4 acc[4] = {};
#pragma unroll
    for (int ch = 0; ch < 16; ++ch) {
        float4 a0 = *(const float4*)(xrow + ch * 32 + lk * 8);
        float4 a1 = *(const float4*)(xrow + ch * 32 + lk * 8 + 4);
        bf16x8 af;
        af[0] = (__bf16)a0.x; af[1] = (__bf16)a0.y;
        af[2] = (__bf16)a0.z; af[3] = (__bf16)a0.w;
        af[4] = (__bf16)a1.x; af[5] = (__bf16)a1.y;
        af[6] = (__bf16)a1.z; af[7] = (__bf16)a1.w;
#pragma unroll
        for (int nt = 0; nt < 4; ++nt) {
            bf16x8 bf = *(const bf16x8*)(W1b + ((size_t)((ch * 4 + lk) * 64) + nt * 16 + lm) * 8);
            acc[nt] = __builtin_amdgcn_mfma_f32_16x16x32_bf16(af, bf, acc[nt], 0, 0, 0);
        }
    }
    int rowbase = blockIdx.x * 64 + wave * 16 + lk * 4;
#pragma unroll
    for (int nt = 0; nt < 4; ++nt) {
#pragma unroll
        for (int j = 0; j < 4; ++j) {
            int gr = rowbase + j;
            if (gr < Nn) h1b[(size_t)gr * 64 + nt * 16 + lm] = (__bf16)acc[nt][j];
        }
    }
#pragma unroll
    for (int nt = 0; nt < 4; ++nt) {
        float ws = asrc[nt * 16 + lm];
        float wd = adst[nt * 16 + lm];
#pragma unroll
        for (int j = 0; j < 4; ++j) {
            float sv = acc[nt][j] * ws;
            float dv = acc[nt][j] * wd;
            sv += __shfl_xor(sv, 1); dv += __shfl_xor(dv, 1);
            sv += __shfl_xor(sv, 2); dv += __shfl_xor(dv, 2);
            sv += __shfl_xor(sv, 4); dv += __shfl_xor(dv, 4);
            int gr = rowbase + j;
            if ((lm & 7) == 0 && gr < Nn) {
                int hh = nt * 2 + (lm >> 3);
                as1[(size_t)gr * 8 + hh] = sv;
                ad1[(size_t)gr * 8 + hh] = dv;
            }
        }
    }
}

// ---------------------------------------------------------------------------
// Layer-1 fused softmax+aggregate + node2. One wave per dst node.
// CONCURRENCY round: launch_bounds(256,8) -> 32 waves/CU (2x prior), VGPR
// capped at 64. Loop trimmed to 4-deep branchless (r6's 8-deep was null and
// would spill at 64 VGPR). 16-lane map: lane = sub*16+c4, bf16x4 gathers.
// Epilogue packs the layer-2 src attention dot into h2 row slot 10.
// ---------------------------------------------------------------------------
__global__ __launch_bounds__(256, 8) void agg1n_k(const int* __restrict__ csr,
                                                  const int* __restrict__ rowptr,
                                                  const float* __restrict__ as1,
                                                  const float* __restrict__ ad1,
                                                  const __bf16* __restrict__ h1b,
                                                  const float* __restrict__ b1,
                                                  const float* __restrict__ W2,
                                                  const float* __restrict__ as2w,
                                                  const float* __restrict__ ad2w,
                                                  float* __restrict__ h2,
                                                  float* __restrict__ ad2, int Nn)
{
    __shared__ float W2s[640];
    for (int i = threadIdx.x; i < 640; i += 256) W2s[i] = W2[i];
    __syncthreads();   // before any early exit (divergent-barrier safety)

    int wid = (blockIdx.x * 256 + threadIdx.x) >> 6;
    if (wid >= Nn) return;
    int lane = threadIdx.x & 63;
    int sub = lane >> 4;        // edge slot 0..3
    int c4 = lane & 15;         // channel group (4 ch)
    int h = c4 >> 1;            // head
    float adv = ad1[(size_t)wid * 8 + h];
    int start = rowptr[wid];
    int len = rowptr[wid + 1] - start;
    float accp = 0.f;
    float4 accv = make_float4(0.f, 0.f, 0.f, 0.f);
    for (int i = sub; i < len; i += 16) {
        int idx = start + i;
        bool k1 = i + 4 < len, k2 = i + 8 < len, k3 = i + 12 < len;
        int s0 = csr[idx];
        int s1 = csr[idx + (k1 ? 4  : 0)];
        int s2 = csr[idx + (k2 ? 8  : 0)];
        int s3 = csr[idx + (k3 ? 12 : 0)];
        float e0 = as1[(size_t)s0 * 8 + h] + adv;
        float e1 = as1[(size_t)s1 * 8 + h] + adv;
        float e2 = as1[(size_t)s2 * 8 + h] + adv;
        float e3 = as1[(size_t)s3 * 8 + h] + adv;
        bf16x4 hv0 = *(const bf16x4*)(h1b + (size_t)s0 * 64 + c4 * 4);
        bf16x4 hv1 = *(const bf16x4*)(h1b + (size_t)s1 * 64 + c4 * 4);
        bf16x4 hv2 = *(const bf16x4*)(h1b + (size_t)s2 * 64 + c4 * 4);
        bf16x4 hv3 = *(const bf16x4*)(h1b + (size_t)s3 * 64 + c4 * 4);
        e0 = e0 > 0.f ? e0 : NEG * e0;
        e1 = e1 > 0.f ? e1 : NEG * e1;
        e2 = e2 > 0.f ? e2 : NEG * e2;
        e3 = e3 > 0.f ? e3 : NEG * e3;
        if (!k1) e1 = -1e30f;           // masked slots -> p = 0 exactly
        if (!k2) e2 = -1e30f;
        if (!k3) e3 = -1e30f;
        float p0 = __expf(e0), p1 = __expf(e1), p2 = __expf(e2), p3 = __expf(e3);
        accp += (p0 + p1) + (p2 + p3);
        accv.x += p0 * (float)hv0[0] + p1 * (float)hv1[0] + p2 * (float)hv2[0] + p3 * (float)hv3[0];
        accv.y += p0 * (float)hv0[1] + p1 * (float)hv1[1] + p2 * (float)hv2[1] + p3 * (float)hv3[1];
        accv.z += p0 * (float)hv0[2] + p1 * (float)hv1[2] + p2 * (float)hv2[2] + p3 * (float)hv3[2];
        accv.w += p0 * (float)hv0[3] + p1 * (float)hv1[3] + p2 * (float)hv2[3] + p3 * (float)hv3[3];
    }
    accp   += __shfl_xor(accp, 16);
    accv.x += __shfl_xor(accv.x, 16);
    accv.y += __shfl_xor(accv.y, 16);
    accv.z += __shfl_xor(accv.z, 16);
    accv.w += __shfl_xor(accv.w, 16);
    accp   += __shfl_xor(accp, 32);
    accv.x += __shfl_xor(accv.x, 32);
    accv.y += __shfl_xor(accv.y, 32);
    accv.z += __shfl_xor(accv.z, 32);
    accv.w += __shfl_xor(accv.w, 32);

    // ---- fused node2: bias + ELU + 64x10 matvec + layer-2 attn dots ----
    float inv = 1.f / (accp + 1e-16f);
    float4 b = *(const float4*)(b1 + c4 * 4);
    float g0 = accv.x * inv + b.x; g0 = g0 > 0.f ? g0 : expm1f(g0);
    float g1 = accv.y * inv + b.y; g1 = g1 > 0.f ? g1 : expm1f(g1);
    float g2 = accv.z * inv + b.z; g2 = g2 > 0.f ? g2 : expm1f(g2);
    float g3 = accv.w * inv + b.w; g3 = g3 > 0.f ? g3 : expm1f(g3);
    int k0 = c4 * 4;
    float aj[10];
#pragma unroll
    for (int j = 0; j < 10; ++j)
        aj[j] = g0 * W2s[(k0 + 0) * 10 + j] + g1 * W2s[(k0 + 1) * 10 + j]
              + g2 * W2s[(k0 + 2) * 10 + j] + g3 * W2s[(k0 + 3) * 10 + j];
#pragma unroll
    for (int m = 1; m <= 8; m <<= 1) {
#pragma unroll
        for (int j = 0; j < 10; ++j) aj[j] += __shfl_xor(aj[j], m);
    }
    if (lane == 0) {
        float s2 = 0.f, d2 = 0.f;
#pragma unroll
        for (int j = 0; j < 10; ++j) { s2 += aj[j] * as2w[j]; d2 += aj[j] * ad2w[j]; }
        *(float4*)(h2 + (size_t)wid * 16 + 0) = make_float4(aj[0], aj[1], aj[2], aj[3]);
        *(float4*)(h2 + (size_t)wid * 16 + 4) = make_float4(aj[4], aj[5], aj[6], aj[7]);
        h2[(size_t)wid * 16 + 8]  = aj[8];
        h2[(size_t)wid * 16 + 9]  = aj[9];
        h2[(size_t)wid * 16 + 10] = s2;     // packed: as2 lives in the same line
        ad2[wid] = d2;
    }
}

// ---------------------------------------------------------------------------
// Layer-2 fused softmax+aggregate + bias + log_softmax. One wave per dst.
// CONCURRENCY round: launch_bounds(256,8) -> 32 waves/CU. Packed gather:
// lane c loads h2row[c]; attention logit from lane sub*16+10 via one shfl.
// ---------------------------------------------------------------------------
__global__ __launch_bounds__(256, 8) void agg2l_k(const int* __restrict__ csr,
                                                  const int* __restrict__ rowptr,
                                                  const float* __restrict__ ad2,
                                                  const float* __restrict__ h2,
                                                  const float* __restrict__ b2,
                                                  float* __restrict__ out, int Nn)
{
    int wid = (blockIdx.x * 256 + threadIdx.x) >> 6;
    if (wid >= Nn) return;
    int lane = threadIdx.x & 63;
    int sub = lane >> 4;
    int c = lane & 15;
    int src10 = (lane & 48) + 10;        // lane holding as2 for this slot
    float adv = ad2[wid];
    int start = rowptr[wid];
    int len = rowptr[wid + 1] - start;
    float accp = 0.f, accv = 0.f;
    int i = sub;
    for (; i + 12 < len; i += 16) {
        int s0 = csr[start + i];
        int s1 = csr[start + i + 4];
        int s2 = csr[start + i + 8];
        int s3 = csr[start + i + 12];
        float v0 = h2[(size_t)s0 * 16 + c];
        float v1 = h2[(size_t)s1 * 16 + c];
        float v2 = h2[(size_t)s2 * 16 + c];
        float v3 = h2[(size_t)s3 * 16 + c];
        float e0 = __shfl(v0, src10) + adv;
        float e1 = __shfl(v1, src10) + adv;
        float e2 = __shfl(v2, src10) + adv;
        float e3 = __shfl(v3, src10) + adv;
        float w0 = (c < 10) ? v0 : 0.f;
        float w1 = (c < 10) ? v1 : 0.f;
        float w2 = (c < 10) ? v2 : 0.f;
        float w3 = (c < 10) ? v3 : 0.f;
        e0 = e0 > 0.f ? e0 : NEG * e0;
        e1 = e1 > 0.f ? e1 : NEG * e1;
        e2 = e2 > 0.f ? e2 : NEG * e2;
        e3 = e3 > 0.f ? e3 : NEG * e3;
        float p0 = __expf(e0), p1 = __expf(e1), p2 = __expf(e2), p3 = __expf(e3);
        accp += (p0 + p1) + (p2 + p3);
        accv += p0 * w0 + p1 * w1 + p2 * w2 + p3 * w3;
    }
    for (; i < len; i += 4) {
        int s0 = csr[start + i];
        float v0 = h2[(size_t)s0 * 16 + c];
        float e0 = __shfl(v0, src10) + adv;
        float w0 = (c < 10) ? v0 : 0.f;
        e0 = e0 > 0.f ? e0 : NEG * e0;
        float p0 = __expf(e0);
        accp += p0;
        accv += p0 * w0;
    }
    accp += __shfl_xor(accp, 16);
    accv += __shfl_xor(accv, 16);
    accp += __shfl_xor(accp, 32);
    accv += __shfl_xor(accv, 32);

    float z = (c < 10) ? accv / (accp + 1e-16f) + b2[c] : -1e30f;
    float m = z;
    m = fmaxf(m, __shfl_xor(m, 1));
    m = fmaxf(m, __shfl_xor(m, 2));
    m = fmaxf(m, __shfl_xor(m, 4));
    m = fmaxf(m, __shfl_xor(m, 8));
    float p = (c < 10) ? expf(z - m) : 0.f;
    p += __shfl_xor(p, 1);
    p += __shfl_xor(p, 2);
    p += __shfl_xor(p, 4);
    p += __shfl_xor(p, 8);
    float lse = m + logf(p);
    if (sub == 0 && c < 10)
        out[(size_t)wid * 10 + c] = z - lse;
}

// ---------------------------------------------------------------------------
extern "C" void kernel_launch(void* const* d_in, const int* in_sizes, int n_in,
                              void* d_out, int out_size, void* d_ws, size_t ws_size,
                              hipStream_t stream)
{
    const float* x     = (const float*)d_in[0];
    const float* W1    = (const float*)d_in[1];
    const float* asrc1 = (const float*)d_in[2];
    const float* adst1 = (const float*)d_in[3];
    const float* b1    = (const float*)d_in[4];
    const float* W2    = (const float*)d_in[5];
    const float* asrc2 = (const float*)d_in[6];
    const float* adst2 = (const float*)d_in[7];
    const float* b2    = (const float*)d_in[8];
    const int*   ei    = (const int*)d_in[9];
    float* out = (float*)d_out;

    int F  = in_sizes[1] / 64;       // 512
    int Nn = in_sizes[0] / F;        // 100000
    int E  = in_sizes[9] / 2;        // 1600000
    int Ep = E + Nn;
    int nbk = (Nn + NPBK - 1) / NPBK;        // 196 buckets
    int nbP = (Ep + CHP - 1) / CHP;          // 416 partition blocks

    float* f = (float*)d_ws;
    __bf16* w1b = (__bf16*)f;  f += 512 * 64 / 2;      // 64KB, 16B-aligned
    __bf16* h1b = (__bf16*)f;  f += (size_t)Nn * 32;   // Nn*64 bf16
    float* as1  = f;  f += (size_t)Nn * 8;
    float* ad1  = f;  f += (size_t)Nn * 8;
    float* h2   = f;  f += (size_t)Nn * 16;            // row: 10 classes + as2@slot10
    float* ad2  = f;  f += Nn;
    int* ip = (int*)f;
    int* rowptr = ip;  ip += Nn + 1;
    int* gcur   = ip;  ip += 256;
    int* ebuf   = ip;  ip += (size_t)nbk * CAPB;       // ~9.6 MB
    int* csr    = ip;  ip += Ep;

    // CSR build: bucketed partition -> per-bucket LDS build (all coalesced)
    hipMemsetAsync(gcur, 0, 256 * sizeof(int), stream);
    part_k<<<16 + nbP, 256, 0, stream>>>(ei, E, Nn, nbk, W1, w1b, gcur, ebuf);
    bucket_k<<<nbk, 256, 0, stream>>>(gcur, nbk, Nn, ebuf, csr, rowptr);

    // Layer-1 GEMM (+attn dots, bf16 h1 store)
    gemm1a_k<<<(Nn + 63) / 64, 256, 0, stream>>>(x, w1b, asrc1, adst1, h1b, as1, ad1, Nn);

    // Layer-1 aggregate + fused node2 (bias/ELU/GEMM2/attn2 dots, packed h2)
    agg1n_k<<<(Nn + 3) / 4, 256, 0, stream>>>(csr, rowptr, as1, ad1, h1b,
                                              b1, W2, asrc2, adst2, h2, ad2, Nn);

    // Layer-2 aggregate + fused bias + log_softmax (one line per edge)
    agg2l_k<<<(Nn + 3) / 4, 256, 0, stream>>>(csr, rowptr, ad2, h2, b2, out, Nn);
}